// Round 1
// baseline (1667.832 us; speedup 1.0000x reference)
//
#include <hip/hip_runtime.h>
#include <math.h>

#define N_NODES 50000
#define E_EDGES 250000
#define HD 256          // H * D
#define NH 4
#define DH 64
#define NC 153

// ---------- float <-> order-preserving uint (for atomic max on floats) ----------
__device__ __forceinline__ unsigned f2ord(float f) {
    unsigned b = __float_as_uint(f);
    return (b & 0x80000000u) ? ~b : (b | 0x80000000u);
}
__device__ __forceinline__ float ord2f(unsigned u) {
    unsigned b = (u & 0x80000000u) ? (u & 0x7fffffffu) : ~u;
    return __uint_as_float(b);
}

// ---------- generic fp32 GEMM: C[M,Nc] = A[M,K] @ B[K,Nc] (+ bias) ----------
// BM=64 BN=64 BK=16, 256 threads, each thread 4x4
#define BM 64
#define BN 64
#define BKg 16
#define TM 4
#define TN 4

__global__ __launch_bounds__(256) void gemm_kernel(
        const float* __restrict__ A, const float* __restrict__ B,
        float* __restrict__ C, const float* __restrict__ bias,
        int M, int Nc, int K) {
    __shared__ float As[BKg][BM + 4];   // A tile, transposed; +4 pad keeps float4 align
    __shared__ float Bs[BKg][BN];
    const int tid = threadIdx.x;
    const int row0 = blockIdx.x * BM;
    const int col0 = blockIdx.y * BN;
    const int tx = tid & 15;        // 0..15 (col groups)
    const int ty = tid >> 4;        // 0..15 (row groups)

    float acc[TM][TN];
    #pragma unroll
    for (int i = 0; i < TM; i++)
        #pragma unroll
        for (int j = 0; j < TN; j++) acc[i][j] = 0.f;

    // A-load mapping: 256 threads x float4 = 64 rows x 16 cols
    const int a_r  = tid >> 2;         // 0..63
    const int a_c4 = (tid & 3) * 4;    // 0,4,8,12
    // B-load mapping: 16 rows x 64 cols
    const int b_r  = tid >> 4;         // 0..15
    const int b_c4 = (tid & 15) * 4;   // 0..60

    for (int k0 = 0; k0 < K; k0 += BKg) {
        float4 av = make_float4(0.f, 0.f, 0.f, 0.f);
        const int ar = row0 + a_r;
        if (ar < M) av = *(const float4*)&A[(size_t)ar * K + k0 + a_c4];
        As[a_c4 + 0][a_r] = av.x;
        As[a_c4 + 1][a_r] = av.y;
        As[a_c4 + 2][a_r] = av.z;
        As[a_c4 + 3][a_r] = av.w;

        float4 bv;
        const int bc = col0 + b_c4;
        const float* Brow = &B[(size_t)(k0 + b_r) * Nc];
        if (bc + 3 < Nc) {
            bv = *(const float4*)&Brow[bc];
        } else {
            bv.x = (bc + 0 < Nc) ? Brow[bc + 0] : 0.f;
            bv.y = (bc + 1 < Nc) ? Brow[bc + 1] : 0.f;
            bv.z = (bc + 2 < Nc) ? Brow[bc + 2] : 0.f;
            bv.w = (bc + 3 < Nc) ? Brow[bc + 3] : 0.f;
        }
        *(float4*)&Bs[b_r][b_c4] = bv;
        __syncthreads();

        #pragma unroll
        for (int k = 0; k < BKg; k++) {
            float4 ra = *(const float4*)&As[k][ty * TM];
            float4 rb = *(const float4*)&Bs[k][tx * TN];
            float fa[TM] = {ra.x, ra.y, ra.z, ra.w};
            float fb[TN] = {rb.x, rb.y, rb.z, rb.w};
            #pragma unroll
            for (int i = 0; i < TM; i++)
                #pragma unroll
                for (int j = 0; j < TN; j++)
                    acc[i][j] = fmaf(fa[i], fb[j], acc[i][j]);
        }
        __syncthreads();
    }

    #pragma unroll
    for (int i = 0; i < TM; i++) {
        const int r = row0 + ty * TM + i;
        if (r >= M) continue;
        #pragma unroll
        for (int j = 0; j < TN; j++) {
            const int c = col0 + tx * TN + j;
            if (c < Nc) {
                float v = acc[i][j];
                if (bias) v += bias[c];
                C[(size_t)r * Nc + c] = v;
            }
        }
    }
}

// ---------- per-node attention scores + reinit of m/z ----------
// one wave per node; lane l covers element h*64+l for h=0..3
__global__ __launch_bounds__(256) void scores_kernel(
        const float* __restrict__ h, const float* __restrict__ asrc,
        const float* __restrict__ adst, float* __restrict__ ssrc,
        float* __restrict__ sdst, unsigned* __restrict__ mkey,
        float* __restrict__ z) {
    const int node = blockIdx.x * 4 + (threadIdx.x >> 6);
    const int lane = threadIdx.x & 63;
    if (node >= N_NODES) return;
    const float* hp = h + (size_t)node * HD;
    float rs[NH], rd[NH];
    #pragma unroll
    for (int hh = 0; hh < NH; hh++) {
        float v = hp[hh * DH + lane];
        rs[hh] = v * asrc[hh * DH + lane];
        rd[hh] = v * adst[hh * DH + lane];
    }
    #pragma unroll
    for (int off = 32; off > 0; off >>= 1) {
        #pragma unroll
        for (int hh = 0; hh < NH; hh++) {
            rs[hh] += __shfl_xor(rs[hh], off);
            rd[hh] += __shfl_xor(rd[hh], off);
        }
    }
    if (lane < NH) {
        // lane hh writes head hh's values (all lanes hold full sums after xor-reduce)
        ssrc[node * NH + lane] = rs[lane];
        sdst[node * NH + lane] = rd[lane];
        mkey[node * NH + lane] = 0u;     // ordered-key of "below -inf"
        z[node * NH + lane]    = 0.f;
    }
}

// ---------- edge pass 1: e = leakyrelu(s_src[src]+s_dst[dst]); segment max ----------
__global__ __launch_bounds__(256) void edge_max_kernel(
        const int* __restrict__ ei, const float* __restrict__ ssrc,
        const float* __restrict__ sdst, float* __restrict__ ebuf,
        unsigned* __restrict__ mkey) {
    const int t = blockIdx.x * blockDim.x + threadIdx.x;
    if (t >= E_EDGES * NH) return;
    const int e = t >> 2, hh = t & 3;
    const int src = ei[e], dst = ei[E_EDGES + e];
    float s = ssrc[src * NH + hh] + sdst[dst * NH + hh];
    s = (s >= 0.f) ? s : 0.2f * s;
    ebuf[t] = s;
    atomicMax(&mkey[dst * NH + hh], f2ord(s));
}

// ---------- edge pass 2: p = exp(e - m[dst]); segment sum ----------
__global__ __launch_bounds__(256) void edge_exp_kernel(
        const int* __restrict__ ei, const unsigned* __restrict__ mkey,
        float* __restrict__ ebuf, float* __restrict__ z) {
    const int t = blockIdx.x * blockDim.x + threadIdx.x;
    if (t >= E_EDGES * NH) return;
    const int e = t >> 2, hh = t & 3;
    const int dst = ei[E_EDGES + e];
    const float m = ord2f(mkey[dst * NH + hh]);
    const float p = expf(ebuf[t] - m);
    ebuf[t] = p;
    atomicAdd(&z[dst * NH + hh], p);
}

// ---------- edge pass 3: acc[dst] += h[src] * alpha ----------
// one wave per edge; lane l covers element h*64+l for h=0..3
__global__ __launch_bounds__(256) void aggregate_kernel(
        const int* __restrict__ ei, const float* __restrict__ hbuf,
        const float* __restrict__ ebuf, const float* __restrict__ z,
        float* __restrict__ acc) {
    const int e = blockIdx.x * 4 + (threadIdx.x >> 6);
    const int lane = threadIdx.x & 63;
    if (e >= E_EDGES) return;
    const int src = ei[e], dst = ei[E_EDGES + e];
    const float* hp = hbuf + (size_t)src * HD;
    float* ap = acc + (size_t)dst * HD;
    #pragma unroll
    for (int hh = 0; hh < NH; hh++) {
        const float alpha = ebuf[e * NH + hh] / (z[dst * NH + hh] + 1e-16f);
        atomicAdd(&ap[hh * DH + lane], hp[hh * DH + lane] * alpha);
    }
}

// ---------- acc init with summed biases ----------
__global__ __launch_bounds__(256) void bias_init_kernel(
        const float* __restrict__ b1, const float* __restrict__ b2,
        float* __restrict__ acc) {
    const int idx = blockIdx.x * 256 + threadIdx.x;
    if (idx >= N_NODES * HD) return;
    const int c = idx & (HD - 1);
    acc[idx] = b1[c] + b2[c];
}

// ---------- in-place leaky relu (slope 0.01) ----------
__global__ __launch_bounds__(256) void leaky_kernel(float* __restrict__ x) {
    const int idx = blockIdx.x * 256 + threadIdx.x;
    if (idx >= N_NODES * HD) return;
    const float v = x[idx];
    x[idx] = (v >= 0.f) ? v : 0.01f * v;
}

// ---------- host-side conv driver ----------
static void run_conv(const float* x, const int* ei, const float* W,
                     const float* asrc, const float* adst,
                     float* buf_h, float* ssrc, float* sdst,
                     unsigned* mkey, float* z, float* ebuf, float* acc,
                     hipStream_t stream) {
    dim3 ggrid((N_NODES + BM - 1) / BM, HD / BN);
    gemm_kernel<<<ggrid, 256, 0, stream>>>(x, W, buf_h, nullptr, N_NODES, HD, HD);
    scores_kernel<<<(N_NODES + 3) / 4, 256, 0, stream>>>(buf_h, asrc, adst,
                                                         ssrc, sdst, mkey, z);
    const int eh_blocks = (E_EDGES * NH + 255) / 256;
    edge_max_kernel<<<eh_blocks, 256, 0, stream>>>(ei, ssrc, sdst, ebuf, mkey);
    edge_exp_kernel<<<eh_blocks, 256, 0, stream>>>(ei, mkey, ebuf, z);
    aggregate_kernel<<<(E_EDGES + 3) / 4, 256, 0, stream>>>(ei, buf_h, ebuf, z, acc);
}

extern "C" void kernel_launch(void* const* d_in, const int* in_sizes, int n_in,
                              void* d_out, int out_size, void* d_ws, size_t ws_size,
                              hipStream_t stream) {
    const float* x    = (const float*)d_in[0];
    const int*   ei_a = (const int*)d_in[1];
    const int*   ei_b = (const int*)d_in[2];
    const float* W0a = (const float*)d_in[3];
    const float* as0a = (const float*)d_in[4];
    const float* ad0a = (const float*)d_in[5];
    const float* b0a = (const float*)d_in[6];
    const float* W0b = (const float*)d_in[7];
    const float* as0b = (const float*)d_in[8];
    const float* ad0b = (const float*)d_in[9];
    const float* b0b = (const float*)d_in[10];
    const float* W1a = (const float*)d_in[11];
    const float* as1a = (const float*)d_in[12];
    const float* ad1a = (const float*)d_in[13];
    const float* b1a = (const float*)d_in[14];
    const float* W1b = (const float*)d_in[15];
    const float* as1b = (const float*)d_in[16];
    const float* ad1b = (const float*)d_in[17];
    const float* b1b = (const float*)d_in[18];
    const float* Wout = (const float*)d_in[19];
    const float* bout = (const float*)d_in[20];
    float* out = (float*)d_out;

    // workspace carve (floats)
    float* ws = (float*)d_ws;
    const size_t NF = (size_t)N_NODES * HD;   // 12.8M
    float* buf_h  = ws;                 // h = x @ W for current conv
    float* acc0   = buf_h + NF;         // layer-0 output / layer-1 input
    float* acc1   = acc0 + NF;          // layer-1 output
    float* ssrc   = acc1 + NF;          // N*4
    float* sdst   = ssrc + (size_t)N_NODES * NH;
    unsigned* mkey = (unsigned*)(sdst + (size_t)N_NODES * NH);
    float* z      = (float*)(mkey + (size_t)N_NODES * NH);
    float* ebuf   = z + (size_t)N_NODES * NH;  // E*4

    const int nf_blocks = (int)((NF + 255) / 256);

    // ---- layer 0 ----
    bias_init_kernel<<<nf_blocks, 256, 0, stream>>>(b0a, b0b, acc0);
    run_conv(x, ei_a, W0a, as0a, ad0a, buf_h, ssrc, sdst, mkey, z, ebuf, acc0, stream);
    run_conv(x, ei_b, W0b, as0b, ad0b, buf_h, ssrc, sdst, mkey, z, ebuf, acc0, stream);
    leaky_kernel<<<nf_blocks, 256, 0, stream>>>(acc0);

    // ---- layer 1 ----
    bias_init_kernel<<<nf_blocks, 256, 0, stream>>>(b1a, b1b, acc1);
    run_conv(acc0, ei_a, W1a, as1a, ad1a, buf_h, ssrc, sdst, mkey, z, ebuf, acc1, stream);
    run_conv(acc0, ei_b, W1b, as1b, ad1b, buf_h, ssrc, sdst, mkey, z, ebuf, acc1, stream);

    // ---- output projection ----
    dim3 ogrid((N_NODES + BM - 1) / BM, (NC + BN - 1) / BN);
    gemm_kernel<<<ogrid, 256, 0, stream>>>(acc1, Wout, out, bout, N_NODES, NC, HD);
}

// Round 2
// 1294.940 us; speedup vs baseline: 1.2880x; 1.2880x over previous
//
#include <hip/hip_runtime.h>
#include <math.h>

#define N_NODES 50000
#define E_EDGES 250000
#define HD 256          // H * D
#define NH 4
#define DH 64
#define NC 153

// ---------- generic fp32 GEMM: C[M,Nc] = A[M,K] @ B[K,Nc] (+ bias) ----------
// BM=64 BN=64 BK=16, 256 threads, each thread 4x4
#define BM 64
#define BN 64
#define BKg 16
#define TM 4
#define TN 4

__global__ __launch_bounds__(256) void gemm_kernel(
        const float* __restrict__ A, const float* __restrict__ B,
        float* __restrict__ C, const float* __restrict__ bias,
        int M, int Nc, int K) {
    __shared__ float As[BKg][BM + 4];
    __shared__ float Bs[BKg][BN];
    const int tid = threadIdx.x;
    const int row0 = blockIdx.x * BM;
    const int col0 = blockIdx.y * BN;
    const int tx = tid & 15;
    const int ty = tid >> 4;

    float acc[TM][TN];
    #pragma unroll
    for (int i = 0; i < TM; i++)
        #pragma unroll
        for (int j = 0; j < TN; j++) acc[i][j] = 0.f;

    const int a_r  = tid >> 2;
    const int a_c4 = (tid & 3) * 4;
    const int b_r  = tid >> 4;
    const int b_c4 = (tid & 15) * 4;

    for (int k0 = 0; k0 < K; k0 += BKg) {
        float4 av = make_float4(0.f, 0.f, 0.f, 0.f);
        const int ar = row0 + a_r;
        if (ar < M) av = *(const float4*)&A[(size_t)ar * K + k0 + a_c4];
        As[a_c4 + 0][a_r] = av.x;
        As[a_c4 + 1][a_r] = av.y;
        As[a_c4 + 2][a_r] = av.z;
        As[a_c4 + 3][a_r] = av.w;

        float4 bv;
        const int bc = col0 + b_c4;
        const float* Brow = &B[(size_t)(k0 + b_r) * Nc];
        if (bc + 3 < Nc) {
            bv = *(const float4*)&Brow[bc];
        } else {
            bv.x = (bc + 0 < Nc) ? Brow[bc + 0] : 0.f;
            bv.y = (bc + 1 < Nc) ? Brow[bc + 1] : 0.f;
            bv.z = (bc + 2 < Nc) ? Brow[bc + 2] : 0.f;
            bv.w = (bc + 3 < Nc) ? Brow[bc + 3] : 0.f;
        }
        *(float4*)&Bs[b_r][b_c4] = bv;
        __syncthreads();

        #pragma unroll
        for (int k = 0; k < BKg; k++) {
            float4 ra = *(const float4*)&As[k][ty * TM];
            float4 rb = *(const float4*)&Bs[k][tx * TN];
            float fa[TM] = {ra.x, ra.y, ra.z, ra.w};
            float fb[TN] = {rb.x, rb.y, rb.z, rb.w};
            #pragma unroll
            for (int i = 0; i < TM; i++)
                #pragma unroll
                for (int j = 0; j < TN; j++)
                    acc[i][j] = fmaf(fa[i], fb[j], acc[i][j]);
        }
        __syncthreads();
    }

    #pragma unroll
    for (int i = 0; i < TM; i++) {
        const int r = row0 + ty * TM + i;
        if (r >= M) continue;
        #pragma unroll
        for (int j = 0; j < TN; j++) {
            const int c = col0 + tx * TN + j;
            if (c < Nc) {
                float v = acc[i][j];
                if (bias) v += bias[c];
                C[(size_t)r * Nc + c] = v;
            }
        }
    }
}

// ---------- CSR construction (per edge type, rebuilt every call) ----------
__global__ __launch_bounds__(256) void zero_int_kernel(int* __restrict__ p, int n) {
    const int i = blockIdx.x * 256 + threadIdx.x;
    if (i < n) p[i] = 0;
}

__global__ __launch_bounds__(256) void hist_kernel(
        const int* __restrict__ ei, int* __restrict__ deg) {
    const int e = blockIdx.x * 256 + threadIdx.x;
    if (e < E_EDGES) atomicAdd(&deg[ei[E_EDGES + e]], 1);
}

// single-block exclusive scan of deg[0..n) -> row_ptr[0..n], cursor copy
__global__ __launch_bounds__(1024) void scan_kernel(
        const int* __restrict__ deg, int* __restrict__ row_ptr,
        int* __restrict__ cursor, int n) {
    __shared__ int sdata[1024];
    __shared__ int srun;
    if (threadIdx.x == 0) srun = 0;
    __syncthreads();
    for (int base = 0; base < n; base += 1024) {
        const int i = base + (int)threadIdx.x;
        const int v = (i < n) ? deg[i] : 0;
        sdata[threadIdx.x] = v;
        __syncthreads();
        for (int off = 1; off < 1024; off <<= 1) {
            int t = (threadIdx.x >= (unsigned)off) ? sdata[threadIdx.x - off] : 0;
            __syncthreads();
            sdata[threadIdx.x] += t;
            __syncthreads();
        }
        const int run = srun;                    // all threads read old running total
        if (i < n) {
            const int excl = run + sdata[threadIdx.x] - v;
            row_ptr[i] = excl;
            cursor[i]  = excl;
        }
        __syncthreads();
        if (threadIdx.x == 1023) srun = run + sdata[1023];
        __syncthreads();
    }
    if (threadIdx.x == 0) row_ptr[n] = srun;
}

__global__ __launch_bounds__(256) void scatter_kernel(
        const int* __restrict__ ei, int* __restrict__ cursor,
        int* __restrict__ col_src) {
    const int e = blockIdx.x * 256 + threadIdx.x;
    if (e >= E_EDGES) return;
    const int src = ei[e], dst = ei[E_EDGES + e];
    const int pos = atomicAdd(&cursor[dst], 1);
    col_src[pos] = src;
}

// ---------- per-node attention scores ----------
// one wave per node; lane l covers element h*64+l for h=0..3
__global__ __launch_bounds__(256) void scores_kernel(
        const float* __restrict__ h, const float* __restrict__ asrc,
        const float* __restrict__ adst, float* __restrict__ ssrc,
        float* __restrict__ sdst) {
    const int node = blockIdx.x * 4 + (threadIdx.x >> 6);
    const int lane = threadIdx.x & 63;
    if (node >= N_NODES) return;
    const float* hp = h + (size_t)node * HD;
    float rs[NH], rd[NH];
    #pragma unroll
    for (int hh = 0; hh < NH; hh++) {
        float v = hp[hh * DH + lane];
        rs[hh] = v * asrc[hh * DH + lane];
        rd[hh] = v * adst[hh * DH + lane];
    }
    #pragma unroll
    for (int off = 32; off > 0; off >>= 1) {
        #pragma unroll
        for (int hh = 0; hh < NH; hh++) {
            rs[hh] += __shfl_xor(rs[hh], off);
            rd[hh] += __shfl_xor(rd[hh], off);
        }
    }
    if (lane < NH) {
        ssrc[node * NH + lane] = rs[lane];
        sdst[node * NH + lane] = rd[lane];
    }
}

// ---------- fused segmented softmax + aggregation, one wave per dst node ----------
// No atomics: each wave exclusively owns its dst row.
__global__ __launch_bounds__(256) void fused_gat_kernel(
        const int* __restrict__ row_ptr, const int* __restrict__ col_src,
        const float* __restrict__ hbuf, const float* __restrict__ ssrc,
        const float* __restrict__ sdst, float* __restrict__ acc) {
    const int node = blockIdx.x * 4 + (threadIdx.x >> 6);
    const int lane = threadIdx.x & 63;
    if (node >= N_NODES) return;
    const int beg = row_ptr[node], end = row_ptr[node + 1];

    float sd[NH];
    #pragma unroll
    for (int hh = 0; hh < NH; hh++) sd[hh] = sdst[node * NH + hh];

    // pass 1: per-head max
    float m[NH];
    #pragma unroll
    for (int hh = 0; hh < NH; hh++) m[hh] = -INFINITY;
    for (int e = beg; e < end; e++) {
        const int src = col_src[e];
        #pragma unroll
        for (int hh = 0; hh < NH; hh++) {
            float s = ssrc[src * NH + hh] + sd[hh];
            s = (s >= 0.f) ? s : 0.2f * s;
            m[hh] = fmaxf(m[hh], s);
        }
    }

    // pass 2: exp, z-sum, weighted feature accumulate
    float z[NH], a[NH];
    #pragma unroll
    for (int hh = 0; hh < NH; hh++) { z[hh] = 0.f; a[hh] = 0.f; }
    for (int e = beg; e < end; e++) {
        const int src = col_src[e];
        const float* hp = hbuf + (size_t)src * HD;
        #pragma unroll
        for (int hh = 0; hh < NH; hh++) {
            float s = ssrc[src * NH + hh] + sd[hh];
            s = (s >= 0.f) ? s : 0.2f * s;
            const float p = expf(s - m[hh]);
            z[hh] += p;
            a[hh] = fmaf(p, hp[hh * DH + lane], a[hh]);
        }
    }

    float* op = acc + (size_t)node * HD;
    #pragma unroll
    for (int hh = 0; hh < NH; hh++) {
        op[hh * DH + lane] += a[hh] / (z[hh] + 1e-16f);
    }
}

// ---------- acc init with summed biases ----------
__global__ __launch_bounds__(256) void bias_init_kernel(
        const float* __restrict__ b1, const float* __restrict__ b2,
        float* __restrict__ acc) {
    const int idx = blockIdx.x * 256 + threadIdx.x;
    if (idx >= N_NODES * HD) return;
    const int c = idx & (HD - 1);
    acc[idx] = b1[c] + b2[c];
}

// ---------- in-place leaky relu (slope 0.01) ----------
__global__ __launch_bounds__(256) void leaky_kernel(float* __restrict__ x) {
    const int idx = blockIdx.x * 256 + threadIdx.x;
    if (idx >= N_NODES * HD) return;
    const float v = x[idx];
    x[idx] = (v >= 0.f) ? v : 0.01f * v;
}

// ---------- host-side conv driver ----------
static void run_conv(const float* x, const int* row_ptr, const int* col_src,
                     const float* W, const float* asrc, const float* adst,
                     float* buf_h, float* ssrc, float* sdst, float* acc,
                     hipStream_t stream) {
    dim3 ggrid((N_NODES + BM - 1) / BM, HD / BN);
    gemm_kernel<<<ggrid, 256, 0, stream>>>(x, W, buf_h, nullptr, N_NODES, HD, HD);
    scores_kernel<<<(N_NODES + 3) / 4, 256, 0, stream>>>(buf_h, asrc, adst, ssrc, sdst);
    fused_gat_kernel<<<(N_NODES + 3) / 4, 256, 0, stream>>>(row_ptr, col_src,
                                                            buf_h, ssrc, sdst, acc);
}

static void build_csr(const int* ei, int* deg, int* cursor, int* row_ptr,
                      int* col_src, hipStream_t stream) {
    const int nb = (N_NODES + 255) / 256;
    const int eb = (E_EDGES + 255) / 256;
    zero_int_kernel<<<nb, 256, 0, stream>>>(deg, N_NODES);
    hist_kernel<<<eb, 256, 0, stream>>>(ei, deg);
    scan_kernel<<<1, 1024, 0, stream>>>(deg, row_ptr, cursor, N_NODES);
    scatter_kernel<<<eb, 256, 0, stream>>>(ei, cursor, col_src);
}

extern "C" void kernel_launch(void* const* d_in, const int* in_sizes, int n_in,
                              void* d_out, int out_size, void* d_ws, size_t ws_size,
                              hipStream_t stream) {
    const float* x    = (const float*)d_in[0];
    const int*   ei_a = (const int*)d_in[1];
    const int*   ei_b = (const int*)d_in[2];
    const float* W0a = (const float*)d_in[3];
    const float* as0a = (const float*)d_in[4];
    const float* ad0a = (const float*)d_in[5];
    const float* b0a = (const float*)d_in[6];
    const float* W0b = (const float*)d_in[7];
    const float* as0b = (const float*)d_in[8];
    const float* ad0b = (const float*)d_in[9];
    const float* b0b = (const float*)d_in[10];
    const float* W1a = (const float*)d_in[11];
    const float* as1a = (const float*)d_in[12];
    const float* ad1a = (const float*)d_in[13];
    const float* b1a = (const float*)d_in[14];
    const float* W1b = (const float*)d_in[15];
    const float* as1b = (const float*)d_in[16];
    const float* ad1b = (const float*)d_in[17];
    const float* b1b = (const float*)d_in[18];
    const float* Wout = (const float*)d_in[19];
    const float* bout = (const float*)d_in[20];
    float* out = (float*)d_out;

    // workspace carve
    float* ws = (float*)d_ws;
    const size_t NF = (size_t)N_NODES * HD;   // 12.8M floats
    float* buf_h  = ws;
    float* acc0   = buf_h + NF;
    float* acc1   = acc0 + NF;
    float* ssrc   = acc1 + NF;                     // N*4
    float* sdst   = ssrc + (size_t)N_NODES * NH;   // N*4
    int*   ibase  = (int*)(sdst + (size_t)N_NODES * NH);
    int* deg     = ibase;                 // N (shared scratch)
    int* cursor  = deg + N_NODES;         // N (shared scratch)
    int* rp_a    = cursor + N_NODES;      // N+1
    int* cs_a    = rp_a + N_NODES + 1;    // E
    int* rp_b    = cs_a + E_EDGES;        // N+1
    int* cs_b    = rp_b + N_NODES + 1;    // E

    const int nf_blocks = (int)((NF + 255) / 256);

    // ---- build CSR for both edge types (reused by both layers) ----
    build_csr(ei_a, deg, cursor, rp_a, cs_a, stream);
    build_csr(ei_b, deg, cursor, rp_b, cs_b, stream);

    // ---- layer 0 ----
    bias_init_kernel<<<nf_blocks, 256, 0, stream>>>(b0a, b0b, acc0);
    run_conv(x, rp_a, cs_a, W0a, as0a, ad0a, buf_h, ssrc, sdst, acc0, stream);
    run_conv(x, rp_b, cs_b, W0b, as0b, ad0b, buf_h, ssrc, sdst, acc0, stream);
    leaky_kernel<<<nf_blocks, 256, 0, stream>>>(acc0);

    // ---- layer 1 ----
    bias_init_kernel<<<nf_blocks, 256, 0, stream>>>(b1a, b1b, acc1);
    run_conv(acc0, rp_a, cs_a, W1a, as1a, ad1a, buf_h, ssrc, sdst, acc1, stream);
    run_conv(acc0, rp_b, cs_b, W1b, as1b, ad1b, buf_h, ssrc, sdst, acc1, stream);

    // ---- output projection ----
    dim3 ogrid((N_NODES + BM - 1) / BM, (NC + BN - 1) / BN);
    gemm_kernel<<<ogrid, 256, 0, stream>>>(acc1, Wout, out, bout, N_NODES, NC, HD);
}

// Round 3
// 1060.723 us; speedup vs baseline: 1.5724x; 1.2208x over previous
//
#include <hip/hip_runtime.h>
#include <math.h>

#define N_NODES 50000
#define E_EDGES 250000
#define HD 256          // H * D
#define NH 4
#define DH 64
#define NC 153
#define KDIM 256        // all GEMMs have K = 256

// ---------- fp32 -> bf16 round-to-nearest-even ----------
__device__ __forceinline__ unsigned short f2bf(float f) {
    unsigned u = __float_as_uint(f);
    u = u + 0x7FFFu + ((u >> 16) & 1u);
    return (unsigned short)(u >> 16);
}

// ================= bf16 MFMA GEMM: C[M,Nc] = A[M,K] @ BT[Nc,K]^T (+bias) =========
// 128x128 block tile, 256 threads = 4 waves (2x2), each wave 64x64 via 4x4 MFMA tiles.
// A and BT staged identically (both [rows][K] bf16), LDS stride 40 (2-way conflicts = free).
typedef __attribute__((ext_vector_type(8))) short bf16x8;
typedef __attribute__((ext_vector_type(4))) float f32x4;
#define LDT 40

__global__ __launch_bounds__(256) void mfma_gemm_bt(
        const unsigned short* __restrict__ A, const unsigned short* __restrict__ BT,
        float* __restrict__ C, const float* __restrict__ bias, int M, int Nc) {
    __shared__ unsigned short As[128 * LDT];
    __shared__ unsigned short Bs[128 * LDT];
    const int tid = threadIdx.x;
    const int lane = tid & 63;
    const int wave = tid >> 6;
    const int wm = (wave & 1) * 64;
    const int wn = (wave >> 1) * 64;
    const int row0 = blockIdx.x * 128;
    const int col0 = blockIdx.y * 128;
    const int quad = lane >> 4;
    const int l16 = lane & 15;

    f32x4 acc[4][4];
    #pragma unroll
    for (int i = 0; i < 4; i++)
        #pragma unroll
        for (int j = 0; j < 4; j++) acc[i][j] = (f32x4)0.f;

    const int s_row = tid >> 2;        // 0..63
    const int s_cg  = (tid & 3) * 8;   // bf16 col offset: 0,8,16,24

    for (int k0 = 0; k0 < KDIM; k0 += 32) {
        #pragma unroll
        for (int h = 0; h < 2; h++) {
            const int r = s_row + h * 64;
            const int gr = row0 + r;
            bf16x8 va = (bf16x8)0;
            if (gr < M) va = *(const bf16x8*)&A[(size_t)gr * KDIM + k0 + s_cg];
            *(bf16x8*)&As[r * LDT + s_cg] = va;
            const int gn = col0 + r;
            bf16x8 vb = (bf16x8)0;
            if (gn < Nc) vb = *(const bf16x8*)&BT[(size_t)gn * KDIM + k0 + s_cg];
            *(bf16x8*)&Bs[r * LDT + s_cg] = vb;
        }
        __syncthreads();

        bf16x8 af[4], bfr[4];
        #pragma unroll
        for (int t = 0; t < 4; t++) {
            af[t]  = *(const bf16x8*)&As[(wm + t * 16 + l16) * LDT + quad * 8];
            bfr[t] = *(const bf16x8*)&Bs[(wn + t * 16 + l16) * LDT + quad * 8];
        }
        #pragma unroll
        for (int mt = 0; mt < 4; mt++)
            #pragma unroll
            for (int nt = 0; nt < 4; nt++)
                acc[mt][nt] = __builtin_amdgcn_mfma_f32_16x16x32_bf16(
                                  af[mt], bfr[nt], acc[mt][nt], 0, 0, 0);
        __syncthreads();
    }

    // epilogue: D col = lane&15, row = quad*4 + reg
    #pragma unroll
    for (int mt = 0; mt < 4; mt++) {
        #pragma unroll
        for (int nt = 0; nt < 4; nt++) {
            const int n = col0 + wn + nt * 16 + l16;
            if (n >= Nc) continue;
            const float bv = bias ? bias[n] : 0.f;
            #pragma unroll
            for (int r = 0; r < 4; r++) {
                const int m = row0 + wm + mt * 16 + quad * 4 + r;
                if (m < M) C[(size_t)m * Nc + n] = acc[mt][nt][r] + bv;
            }
        }
    }
}

// ---------- fp32 -> bf16 conversion (vectorized) ----------
__global__ __launch_bounds__(256) void convert_bf16_kernel(
        const float* __restrict__ in, unsigned short* __restrict__ out, int n) {
    const int i = (blockIdx.x * 256 + threadIdx.x) * 4;
    if (i + 3 < n) {
        const float4 v = *(const float4*)&in[i];
        ushort4 o;
        o.x = f2bf(v.x); o.y = f2bf(v.y); o.z = f2bf(v.z); o.w = f2bf(v.w);
        *(ushort4*)&out[i] = o;
    } else {
        for (int j = i; j < n; j++) out[j] = f2bf(in[j]);
    }
}

// ---------- fused leaky-relu (0.01) in-place + bf16 copy ----------
__global__ __launch_bounds__(256) void leaky_bf16_kernel(
        float* __restrict__ x, unsigned short* __restrict__ out) {
    const int i = (blockIdx.x * 256 + threadIdx.x) * 4;
    if (i >= N_NODES * HD) return;
    float4 v = *(float4*)&x[i];
    v.x = (v.x >= 0.f) ? v.x : 0.01f * v.x;
    v.y = (v.y >= 0.f) ? v.y : 0.01f * v.y;
    v.z = (v.z >= 0.f) ? v.z : 0.01f * v.z;
    v.w = (v.w >= 0.f) ? v.w : 0.01f * v.w;
    *(float4*)&x[i] = v;
    ushort4 o;
    o.x = f2bf(v.x); o.y = f2bf(v.y); o.z = f2bf(v.z); o.w = f2bf(v.w);
    *(ushort4*)&out[i] = o;
}

// ---------- weight transpose+convert: W[K,Nc] fp32 -> Wt[Nc,K] bf16 ----------
__global__ __launch_bounds__(256) void wt_kernel(
        const float* __restrict__ W, unsigned short* __restrict__ Wt, int Nc) {
    const int idx = blockIdx.x * 256 + threadIdx.x;   // = n*KDIM + k
    const int n = idx >> 8, k = idx & 255;
    if (n < Nc) Wt[idx] = f2bf(W[(size_t)k * Nc + n]);
}

// ---------- CSR construction ----------
__global__ __launch_bounds__(256) void zero_int_kernel(int* __restrict__ p, int n) {
    const int i = blockIdx.x * 256 + threadIdx.x;
    if (i < n) p[i] = 0;
}

__global__ __launch_bounds__(256) void hist_kernel(
        const int* __restrict__ ei, int* __restrict__ deg) {
    const int e = blockIdx.x * 256 + threadIdx.x;
    if (e < E_EDGES) atomicAdd(&deg[ei[E_EDGES + e]], 1);
}

__global__ __launch_bounds__(1024) void scan_kernel(
        const int* __restrict__ deg, int* __restrict__ row_ptr,
        int* __restrict__ cursor, int n) {
    __shared__ int sdata[1024];
    __shared__ int srun;
    if (threadIdx.x == 0) srun = 0;
    __syncthreads();
    for (int base = 0; base < n; base += 1024) {
        const int i = base + (int)threadIdx.x;
        const int v = (i < n) ? deg[i] : 0;
        sdata[threadIdx.x] = v;
        __syncthreads();
        for (int off = 1; off < 1024; off <<= 1) {
            int t = (threadIdx.x >= (unsigned)off) ? sdata[threadIdx.x - off] : 0;
            __syncthreads();
            sdata[threadIdx.x] += t;
            __syncthreads();
        }
        const int run = srun;
        if (i < n) {
            const int excl = run + sdata[threadIdx.x] - v;
            row_ptr[i] = excl;
            cursor[i]  = excl;
        }
        __syncthreads();
        if (threadIdx.x == 1023) srun = run + sdata[1023];
        __syncthreads();
    }
    if (threadIdx.x == 0) row_ptr[n] = srun;
}

__global__ __launch_bounds__(256) void scatter_kernel(
        const int* __restrict__ ei, int* __restrict__ cursor,
        int* __restrict__ col_src) {
    const int e = blockIdx.x * 256 + threadIdx.x;
    if (e >= E_EDGES) return;
    const int src = ei[e], dst = ei[E_EDGES + e];
    const int pos = atomicAdd(&cursor[dst], 1);
    col_src[pos] = src;
}

// ---------- per-node attention scores ----------
__global__ __launch_bounds__(256) void scores_kernel(
        const float* __restrict__ h, const float* __restrict__ asrc,
        const float* __restrict__ adst, float* __restrict__ ssrc,
        float* __restrict__ sdst) {
    const int node = blockIdx.x * 4 + (threadIdx.x >> 6);
    const int lane = threadIdx.x & 63;
    if (node >= N_NODES) return;
    const float* hp = h + (size_t)node * HD;
    float rs[NH], rd[NH];
    #pragma unroll
    for (int hh = 0; hh < NH; hh++) {
        float v = hp[hh * DH + lane];
        rs[hh] = v * asrc[hh * DH + lane];
        rd[hh] = v * adst[hh * DH + lane];
    }
    #pragma unroll
    for (int off = 32; off > 0; off >>= 1) {
        #pragma unroll
        for (int hh = 0; hh < NH; hh++) {
            rs[hh] += __shfl_xor(rs[hh], off);
            rd[hh] += __shfl_xor(rd[hh], off);
        }
    }
    if (lane < NH) {
        ssrc[node * NH + lane] = rs[lane];
        sdst[node * NH + lane] = rd[lane];
    }
}

// ---------- fused segmented softmax + aggregation, one wave per dst node ----------
__global__ __launch_bounds__(256) void fused_gat_kernel(
        const int* __restrict__ row_ptr, const int* __restrict__ col_src,
        const float* __restrict__ hbuf, const float* __restrict__ ssrc,
        const float* __restrict__ sdst, float* __restrict__ acc) {
    const int node = blockIdx.x * 4 + (threadIdx.x >> 6);
    const int lane = threadIdx.x & 63;
    if (node >= N_NODES) return;
    const int beg = row_ptr[node], end = row_ptr[node + 1];

    float sd[NH];
    #pragma unroll
    for (int hh = 0; hh < NH; hh++) sd[hh] = sdst[node * NH + hh];

    float m[NH];
    #pragma unroll
    for (int hh = 0; hh < NH; hh++) m[hh] = -INFINITY;
    for (int e = beg; e < end; e++) {
        const int src = col_src[e];
        #pragma unroll
        for (int hh = 0; hh < NH; hh++) {
            float s = ssrc[src * NH + hh] + sd[hh];
            s = (s >= 0.f) ? s : 0.2f * s;
            m[hh] = fmaxf(m[hh], s);
        }
    }

    float z[NH], a[NH];
    #pragma unroll
    for (int hh = 0; hh < NH; hh++) { z[hh] = 0.f; a[hh] = 0.f; }
    for (int e = beg; e < end; e++) {
        const int src = col_src[e];
        const float* hp = hbuf + (size_t)src * HD;
        #pragma unroll
        for (int hh = 0; hh < NH; hh++) {
            float s = ssrc[src * NH + hh] + sd[hh];
            s = (s >= 0.f) ? s : 0.2f * s;
            const float p = expf(s - m[hh]);
            z[hh] += p;
            a[hh] = fmaf(p, hp[hh * DH + lane], a[hh]);
        }
    }

    float* op = acc + (size_t)node * HD;
    #pragma unroll
    for (int hh = 0; hh < NH; hh++) {
        op[hh * DH + lane] += a[hh] / (z[hh] + 1e-16f);
    }
}

// ---------- acc init with summed biases ----------
__global__ __launch_bounds__(256) void bias_init_kernel(
        const float* __restrict__ b1, const float* __restrict__ b2,
        float* __restrict__ acc) {
    const int idx = blockIdx.x * 256 + threadIdx.x;
    if (idx >= N_NODES * HD) return;
    const int c = idx & (HD - 1);
    acc[idx] = b1[c] + b2[c];
}

// ---------- host-side helpers ----------
static void run_conv(const unsigned short* a_bf, const int* row_ptr, const int* col_src,
                     const float* W, const float* asrc, const float* adst,
                     unsigned short* Wt, float* buf_h, float* ssrc, float* sdst,
                     float* acc, hipStream_t stream) {
    wt_kernel<<<HD, 256, 0, stream>>>(W, Wt, HD);
    dim3 ggrid((N_NODES + 127) / 128, (HD + 127) / 128);
    mfma_gemm_bt<<<ggrid, 256, 0, stream>>>(a_bf, Wt, buf_h, nullptr, N_NODES, HD);
    scores_kernel<<<(N_NODES + 3) / 4, 256, 0, stream>>>(buf_h, asrc, adst, ssrc, sdst);
    fused_gat_kernel<<<(N_NODES + 3) / 4, 256, 0, stream>>>(row_ptr, col_src,
                                                            buf_h, ssrc, sdst, acc);
}

static void build_csr(const int* ei, int* deg, int* cursor, int* row_ptr,
                      int* col_src, hipStream_t stream) {
    const int nb = (N_NODES + 255) / 256;
    const int eb = (E_EDGES + 255) / 256;
    zero_int_kernel<<<nb, 256, 0, stream>>>(deg, N_NODES);
    hist_kernel<<<eb, 256, 0, stream>>>(ei, deg);
    scan_kernel<<<1, 1024, 0, stream>>>(deg, row_ptr, cursor, N_NODES);
    scatter_kernel<<<eb, 256, 0, stream>>>(ei, cursor, col_src);
}

extern "C" void kernel_launch(void* const* d_in, const int* in_sizes, int n_in,
                              void* d_out, int out_size, void* d_ws, size_t ws_size,
                              hipStream_t stream) {
    const float* x    = (const float*)d_in[0];
    const int*   ei_a = (const int*)d_in[1];
    const int*   ei_b = (const int*)d_in[2];
    const float* W0a = (const float*)d_in[3];
    const float* as0a = (const float*)d_in[4];
    const float* ad0a = (const float*)d_in[5];
    const float* b0a = (const float*)d_in[6];
    const float* W0b = (const float*)d_in[7];
    const float* as0b = (const float*)d_in[8];
    const float* ad0b = (const float*)d_in[9];
    const float* b0b = (const float*)d_in[10];
    const float* W1a = (const float*)d_in[11];
    const float* as1a = (const float*)d_in[12];
    const float* ad1a = (const float*)d_in[13];
    const float* b1a = (const float*)d_in[14];
    const float* W1b = (const float*)d_in[15];
    const float* as1b = (const float*)d_in[16];
    const float* ad1b = (const float*)d_in[17];
    const float* b1b = (const float*)d_in[18];
    const float* Wout = (const float*)d_in[19];
    const float* bout = (const float*)d_in[20];
    float* out = (float*)d_out;

    // workspace carve
    float* ws = (float*)d_ws;
    const size_t NF = (size_t)N_NODES * HD;   // 12.8M
    float* buf_h  = ws;                         // NF
    float* acc0   = buf_h + NF;                 // NF
    float* acc1   = acc0 + NF;                  // NF
    unsigned short* bf_in = (unsigned short*)(acc1 + NF);       // NF ushort (reused 3x)
    unsigned short* Wt    = bf_in + NF;                         // 256*256 ushort
    float* ssrc   = (float*)(Wt + (size_t)KDIM * KDIM);         // N*4
    float* sdst   = ssrc + (size_t)N_NODES * NH;                // N*4
    int*   ibase  = (int*)(sdst + (size_t)N_NODES * NH);
    int* deg     = ibase;
    int* cursor  = deg + N_NODES;
    int* rp_a    = cursor + N_NODES;
    int* cs_a    = rp_a + N_NODES + 1;
    int* rp_b    = cs_a + E_EDGES;
    int* cs_b    = rp_b + N_NODES + 1;

    const int nf_blocks  = (int)((NF + 255) / 256);
    const int nf4_blocks = (int)((NF / 4 + 255) / 256);

    // ---- CSR for both edge types (reused by both layers) ----
    build_csr(ei_a, deg, cursor, rp_a, cs_a, stream);
    build_csr(ei_b, deg, cursor, rp_b, cs_b, stream);

    // ---- layer 0 ----
    convert_bf16_kernel<<<nf4_blocks, 256, 0, stream>>>(x, bf_in, (int)NF);
    bias_init_kernel<<<nf_blocks, 256, 0, stream>>>(b0a, b0b, acc0);
    run_conv(bf_in, rp_a, cs_a, W0a, as0a, ad0a, Wt, buf_h, ssrc, sdst, acc0, stream);
    run_conv(bf_in, rp_b, cs_b, W0b, as0b, ad0b, Wt, buf_h, ssrc, sdst, acc0, stream);
    leaky_bf16_kernel<<<nf4_blocks, 256, 0, stream>>>(acc0, bf_in);  // acc0 in-place + bf16

    // ---- layer 1 ----
    bias_init_kernel<<<nf_blocks, 256, 0, stream>>>(b1a, b1b, acc1);
    run_conv(bf_in, rp_a, cs_a, W1a, as1a, ad1a, Wt, buf_h, ssrc, sdst, acc1, stream);
    run_conv(bf_in, rp_b, cs_b, W1b, as1b, ad1b, Wt, buf_h, ssrc, sdst, acc1, stream);

    // ---- output projection ----
    convert_bf16_kernel<<<nf4_blocks, 256, 0, stream>>>(acc1, bf_in, (int)NF);
    wt_kernel<<<NC, 256, 0, stream>>>(Wout, Wt, NC);
    dim3 ogrid((N_NODES + 127) / 128, (NC + 127) / 128);
    mfma_gemm_bt<<<ogrid, 256, 0, stream>>>(bf_in, Wt, out, bout, N_NODES, NC);
}

// Round 4
// 890.790 us; speedup vs baseline: 1.8723x; 1.1908x over previous
//
#include <hip/hip_runtime.h>
#include <math.h>

#define N_NODES 50000
#define E_EDGES 250000
#define HD 256          // H * D
#define NH 4
#define DH 64
#define NC 153
#define KDIM 256        // all GEMMs have K = 256

// ---------- fp32 -> bf16 round-to-nearest-even ----------
__device__ __forceinline__ unsigned short f2bf(float f) {
    unsigned u = __float_as_uint(f);
    u = u + 0x7FFFu + ((u >> 16) & 1u);
    return (unsigned short)(u >> 16);
}

// ================= bf16 MFMA GEMM: C[M,Nc] = A[M,K] @ BT[Nc,K]^T (+bias) =========
// 128x128 block tile, 256 threads = 4 waves (2x2), each wave 64x64 via 4x4 MFMA tiles.
typedef __attribute__((ext_vector_type(8))) short bf16x8;
typedef __attribute__((ext_vector_type(4))) float f32x4;
#define LDT 40

__global__ __launch_bounds__(256) void mfma_gemm_bt(
        const unsigned short* __restrict__ A, const unsigned short* __restrict__ BT,
        float* __restrict__ C, const float* __restrict__ bias, int M, int Nc) {
    __shared__ unsigned short As[128 * LDT];
    __shared__ unsigned short Bs[128 * LDT];
    const int tid = threadIdx.x;
    const int lane = tid & 63;
    const int wave = tid >> 6;
    const int wm = (wave & 1) * 64;
    const int wn = (wave >> 1) * 64;
    const int row0 = blockIdx.x * 128;
    const int col0 = blockIdx.y * 128;
    const int quad = lane >> 4;
    const int l16 = lane & 15;

    f32x4 acc[4][4];
    #pragma unroll
    for (int i = 0; i < 4; i++)
        #pragma unroll
        for (int j = 0; j < 4; j++) acc[i][j] = (f32x4)0.f;

    const int s_row = tid >> 2;        // 0..63
    const int s_cg  = (tid & 3) * 8;   // bf16 col offset: 0,8,16,24

    for (int k0 = 0; k0 < KDIM; k0 += 32) {
        #pragma unroll
        for (int h = 0; h < 2; h++) {
            const int r = s_row + h * 64;
            const int gr = row0 + r;
            bf16x8 va = (bf16x8)0;
            if (gr < M) va = *(const bf16x8*)&A[(size_t)gr * KDIM + k0 + s_cg];
            *(bf16x8*)&As[r * LDT + s_cg] = va;
            const int gn = col0 + r;
            bf16x8 vb = (bf16x8)0;
            if (gn < Nc) vb = *(const bf16x8*)&BT[(size_t)gn * KDIM + k0 + s_cg];
            *(bf16x8*)&Bs[r * LDT + s_cg] = vb;
        }
        __syncthreads();

        bf16x8 af[4], bfr[4];
        #pragma unroll
        for (int t = 0; t < 4; t++) {
            af[t]  = *(const bf16x8*)&As[(wm + t * 16 + l16) * LDT + quad * 8];
            bfr[t] = *(const bf16x8*)&Bs[(wn + t * 16 + l16) * LDT + quad * 8];
        }
        #pragma unroll
        for (int mt = 0; mt < 4; mt++)
            #pragma unroll
            for (int nt = 0; nt < 4; nt++)
                acc[mt][nt] = __builtin_amdgcn_mfma_f32_16x16x32_bf16(
                                  af[mt], bfr[nt], acc[mt][nt], 0, 0, 0);
        __syncthreads();
    }

    // epilogue: D col = lane&15, row = quad*4 + reg
    #pragma unroll
    for (int mt = 0; mt < 4; mt++) {
        #pragma unroll
        for (int nt = 0; nt < 4; nt++) {
            const int n = col0 + wn + nt * 16 + l16;
            if (n >= Nc) continue;
            const float bv = bias ? bias[n] : 0.f;
            #pragma unroll
            for (int r = 0; r < 4; r++) {
                const int m = row0 + wm + mt * 16 + quad * 4 + r;
                if (m < M) C[(size_t)m * Nc + n] = acc[mt][nt][r] + bv;
            }
        }
    }
}

// ---------- fp32 -> bf16 conversion (vectorized) ----------
__global__ __launch_bounds__(256) void convert_bf16_kernel(
        const float* __restrict__ in, unsigned short* __restrict__ out, int n) {
    const int i = (blockIdx.x * 256 + threadIdx.x) * 4;
    if (i + 3 < n) {
        const float4 v = *(const float4*)&in[i];
        ushort4 o;
        o.x = f2bf(v.x); o.y = f2bf(v.y); o.z = f2bf(v.z); o.w = f2bf(v.w);
        *(ushort4*)&out[i] = o;
    } else {
        for (int j = i; j < n; j++) out[j] = f2bf(in[j]);
    }
}

// ---------- fused leaky-relu (0.01) in-place + bf16 copy ----------
__global__ __launch_bounds__(256) void leaky_bf16_kernel(
        float* __restrict__ x, unsigned short* __restrict__ out) {
    const int i = (blockIdx.x * 256 + threadIdx.x) * 4;
    if (i >= N_NODES * HD) return;
    float4 v = *(float4*)&x[i];
    v.x = (v.x >= 0.f) ? v.x : 0.01f * v.x;
    v.y = (v.y >= 0.f) ? v.y : 0.01f * v.y;
    v.z = (v.z >= 0.f) ? v.z : 0.01f * v.z;
    v.w = (v.w >= 0.f) ? v.w : 0.01f * v.w;
    *(float4*)&x[i] = v;
    ushort4 o;
    o.x = f2bf(v.x); o.y = f2bf(v.y); o.z = f2bf(v.z); o.w = f2bf(v.w);
    *(ushort4*)&out[i] = o;
}

// ---------- weight transpose+convert: W[K,Nc] fp32 -> Wt[Nc,K] bf16 ----------
__global__ __launch_bounds__(256) void wt_kernel(
        const float* __restrict__ W, unsigned short* __restrict__ Wt, int Nc) {
    const int idx = blockIdx.x * 256 + threadIdx.x;   // = n*KDIM + k
    const int n = idx >> 8, k = idx & 255;
    if (n < Nc) Wt[idx] = f2bf(W[(size_t)k * Nc + n]);
}

// ---------- CSR construction ----------
__global__ __launch_bounds__(256) void zero_int_kernel(int* __restrict__ p, int n) {
    const int i = blockIdx.x * 256 + threadIdx.x;
    if (i < n) p[i] = 0;
}

__global__ __launch_bounds__(256) void hist_kernel(
        const int* __restrict__ ei, int* __restrict__ deg) {
    const int e = blockIdx.x * 256 + threadIdx.x;
    if (e < E_EDGES) atomicAdd(&deg[ei[E_EDGES + e]], 1);
}

// --- hierarchical scan: local (per-1024-block) -> block sums -> add offsets ---
__global__ __launch_bounds__(1024) void scan_local_kernel(
        const int* __restrict__ deg, int* __restrict__ excl,
        int* __restrict__ bsums, int n) {
    __shared__ int wsum[16];
    const int i = blockIdx.x * 1024 + threadIdx.x;
    const int lane = threadIdx.x & 63;
    const int wid = threadIdx.x >> 6;
    const int v = (i < n) ? deg[i] : 0;
    int s = v;
    #pragma unroll
    for (int off = 1; off < 64; off <<= 1) {
        const int t = __shfl_up(s, off);
        if (lane >= off) s += t;
    }
    if (lane == 63) wsum[wid] = s;
    __syncthreads();
    if (wid == 0) {
        int wv = (lane < 16) ? wsum[lane] : 0;
        #pragma unroll
        for (int off = 1; off < 16; off <<= 1) {
            const int t = __shfl_up(wv, off);
            if (lane >= off) wv += t;
        }
        if (lane < 16) wsum[lane] = wv;
    }
    __syncthreads();
    const int woff = (wid > 0) ? wsum[wid - 1] : 0;
    if (i < n) excl[i] = s - v + woff;
    if (threadIdx.x == 1023) bsums[blockIdx.x] = wsum[15];
}

// single wave scans <=64 block sums in-place to exclusive offsets; writes total
__global__ __launch_bounds__(64) void scan_bsums_kernel(
        int* __restrict__ bsums, int* __restrict__ row_ptr, int nb, int n) {
    const int lane = threadIdx.x;
    const int v = (lane < nb) ? bsums[lane] : 0;
    int s = v;
    #pragma unroll
    for (int off = 1; off < 64; off <<= 1) {
        const int t = __shfl_up(s, off);
        if (lane >= off) s += t;
    }
    if (lane < nb) bsums[lane] = s - v;
    if (lane == 63) row_ptr[n] = s;
}

__global__ __launch_bounds__(256) void scan_add_kernel(
        const int* __restrict__ excl, const int* __restrict__ bsums,
        int* __restrict__ row_ptr, int* __restrict__ cursor, int n) {
    const int i = blockIdx.x * 256 + threadIdx.x;
    if (i >= n) return;
    const int v = excl[i] + bsums[i >> 10];
    row_ptr[i] = v;
    cursor[i]  = v;
}

__global__ __launch_bounds__(256) void scatter_kernel(
        const int* __restrict__ ei, int* __restrict__ cursor,
        int* __restrict__ col_src) {
    const int e = blockIdx.x * 256 + threadIdx.x;
    if (e >= E_EDGES) return;
    const int src = ei[e], dst = ei[E_EDGES + e];
    const int pos = atomicAdd(&cursor[dst], 1);
    col_src[pos] = src;
}

// ---------- per-node attention scores ----------
__global__ __launch_bounds__(256) void scores_kernel(
        const float* __restrict__ h, const float* __restrict__ asrc,
        const float* __restrict__ adst, float* __restrict__ ssrc,
        float* __restrict__ sdst) {
    const int node = blockIdx.x * 4 + (threadIdx.x >> 6);
    const int lane = threadIdx.x & 63;
    if (node >= N_NODES) return;
    const float* hp = h + (size_t)node * HD;
    float rs[NH], rd[NH];
    #pragma unroll
    for (int hh = 0; hh < NH; hh++) {
        float v = hp[hh * DH + lane];
        rs[hh] = v * asrc[hh * DH + lane];
        rd[hh] = v * adst[hh * DH + lane];
    }
    #pragma unroll
    for (int off = 32; off > 0; off >>= 1) {
        #pragma unroll
        for (int hh = 0; hh < NH; hh++) {
            rs[hh] += __shfl_xor(rs[hh], off);
            rd[hh] += __shfl_xor(rd[hh], off);
        }
    }
    if (lane < NH) {
        ssrc[node * NH + lane] = rs[lane];
        sdst[node * NH + lane] = rd[lane];
    }
}

// ---------- fused segmented softmax + aggregation, one wave per dst node ----------
__global__ __launch_bounds__(256) void fused_gat_kernel(
        const int* __restrict__ row_ptr, const int* __restrict__ col_src,
        const float* __restrict__ hbuf, const float* __restrict__ ssrc,
        const float* __restrict__ sdst, float* __restrict__ acc) {
    const int node = blockIdx.x * 4 + (threadIdx.x >> 6);
    const int lane = threadIdx.x & 63;
    if (node >= N_NODES) return;
    const int beg = row_ptr[node], end = row_ptr[node + 1];

    float sd[NH];
    #pragma unroll
    for (int hh = 0; hh < NH; hh++) sd[hh] = sdst[node * NH + hh];

    float m[NH];
    #pragma unroll
    for (int hh = 0; hh < NH; hh++) m[hh] = -INFINITY;
    for (int e = beg; e < end; e++) {
        const int src = col_src[e];
        #pragma unroll
        for (int hh = 0; hh < NH; hh++) {
            float s = ssrc[src * NH + hh] + sd[hh];
            s = (s >= 0.f) ? s : 0.2f * s;
            m[hh] = fmaxf(m[hh], s);
        }
    }

    float z[NH], a[NH];
    #pragma unroll
    for (int hh = 0; hh < NH; hh++) { z[hh] = 0.f; a[hh] = 0.f; }
    for (int e = beg; e < end; e++) {
        const int src = col_src[e];
        const float* hp = hbuf + (size_t)src * HD;
        #pragma unroll
        for (int hh = 0; hh < NH; hh++) {
            float s = ssrc[src * NH + hh] + sd[hh];
            s = (s >= 0.f) ? s : 0.2f * s;
            const float p = expf(s - m[hh]);
            z[hh] += p;
            a[hh] = fmaf(p, hp[hh * DH + lane], a[hh]);
        }
    }

    float* op = acc + (size_t)node * HD;
    #pragma unroll
    for (int hh = 0; hh < NH; hh++) {
        op[hh * DH + lane] += a[hh] / (z[hh] + 1e-16f);
    }
}

// ---------- acc init with summed biases ----------
__global__ __launch_bounds__(256) void bias_init_kernel(
        const float* __restrict__ b1, const float* __restrict__ b2,
        float* __restrict__ acc) {
    const int idx = blockIdx.x * 256 + threadIdx.x;
    if (idx >= N_NODES * HD) return;
    const int c = idx & (HD - 1);
    acc[idx] = b1[c] + b2[c];
}

// ---------- host-side helpers ----------
static void run_conv(const unsigned short* a_bf, const int* row_ptr, const int* col_src,
                     const float* W, const float* asrc, const float* adst,
                     unsigned short* Wt, float* buf_h, float* ssrc, float* sdst,
                     float* acc, hipStream_t stream) {
    wt_kernel<<<HD, 256, 0, stream>>>(W, Wt, HD);
    dim3 ggrid((N_NODES + 127) / 128, (HD + 127) / 128);
    mfma_gemm_bt<<<ggrid, 256, 0, stream>>>(a_bf, Wt, buf_h, nullptr, N_NODES, HD);
    scores_kernel<<<(N_NODES + 3) / 4, 256, 0, stream>>>(buf_h, asrc, adst, ssrc, sdst);
    fused_gat_kernel<<<(N_NODES + 3) / 4, 256, 0, stream>>>(row_ptr, col_src,
                                                            buf_h, ssrc, sdst, acc);
}

static void build_csr(const int* ei, int* deg, int* cursor, int* row_ptr,
                      int* col_src, int* excl, int* bsums, hipStream_t stream) {
    const int nb  = (N_NODES + 255) / 256;
    const int eb  = (E_EDGES + 255) / 256;
    const int sb  = (N_NODES + 1023) / 1024;   // 49 blocks
    zero_int_kernel<<<nb, 256, 0, stream>>>(deg, N_NODES);
    hist_kernel<<<eb, 256, 0, stream>>>(ei, deg);
    scan_local_kernel<<<sb, 1024, 0, stream>>>(deg, excl, bsums, N_NODES);
    scan_bsums_kernel<<<1, 64, 0, stream>>>(bsums, row_ptr, sb, N_NODES);
    scan_add_kernel<<<nb, 256, 0, stream>>>(excl, bsums, row_ptr, cursor, N_NODES);
    scatter_kernel<<<eb, 256, 0, stream>>>(ei, cursor, col_src);
}

extern "C" void kernel_launch(void* const* d_in, const int* in_sizes, int n_in,
                              void* d_out, int out_size, void* d_ws, size_t ws_size,
                              hipStream_t stream) {
    const float* x    = (const float*)d_in[0];
    const int*   ei_a = (const int*)d_in[1];
    const int*   ei_b = (const int*)d_in[2];
    const float* W0a = (const float*)d_in[3];
    const float* as0a = (const float*)d_in[4];
    const float* ad0a = (const float*)d_in[5];
    const float* b0a = (const float*)d_in[6];
    const float* W0b = (const float*)d_in[7];
    const float* as0b = (const float*)d_in[8];
    const float* ad0b = (const float*)d_in[9];
    const float* b0b = (const float*)d_in[10];
    const float* W1a = (const float*)d_in[11];
    const float* as1a = (const float*)d_in[12];
    const float* ad1a = (const float*)d_in[13];
    const float* b1a = (const float*)d_in[14];
    const float* W1b = (const float*)d_in[15];
    const float* as1b = (const float*)d_in[16];
    const float* ad1b = (const float*)d_in[17];
    const float* b1b = (const float*)d_in[18];
    const float* Wout = (const float*)d_in[19];
    const float* bout = (const float*)d_in[20];
    float* out = (float*)d_out;

    // workspace carve
    float* ws = (float*)d_ws;
    const size_t NF = (size_t)N_NODES * HD;   // 12.8M
    float* buf_h  = ws;                         // NF
    float* acc0   = buf_h + NF;                 // NF
    float* acc1   = acc0 + NF;                  // NF
    unsigned short* bf_in = (unsigned short*)(acc1 + NF);       // NF ushort (reused 3x)
    unsigned short* Wt    = bf_in + NF;                         // 256*256 ushort
    float* ssrc   = (float*)(Wt + (size_t)KDIM * KDIM);         // N*4
    float* sdst   = ssrc + (size_t)N_NODES * NH;                // N*4
    int*   ibase  = (int*)(sdst + (size_t)N_NODES * NH);
    int* deg     = ibase;
    int* cursor  = deg + N_NODES;
    int* rp_a    = cursor + N_NODES;
    int* cs_a    = rp_a + N_NODES + 1;
    int* rp_b    = cs_a + E_EDGES;
    int* cs_b    = rp_b + N_NODES + 1;
    int* excl    = cs_b + E_EDGES;        // N
    int* bsums   = excl + N_NODES;        // 64

    const int nf_blocks  = (int)((NF + 255) / 256);
    const int nf4_blocks = (int)((NF / 4 + 255) / 256);

    // ---- CSR for both edge types (reused by both layers) ----
    build_csr(ei_a, deg, cursor, rp_a, cs_a, excl, bsums, stream);
    build_csr(ei_b, deg, cursor, rp_b, cs_b, excl, bsums, stream);

    // ---- layer 0 ----
    convert_bf16_kernel<<<nf4_blocks, 256, 0, stream>>>(x, bf_in, (int)NF);
    bias_init_kernel<<<nf_blocks, 256, 0, stream>>>(b0a, b0b, acc0);
    run_conv(bf_in, rp_a, cs_a, W0a, as0a, ad0a, Wt, buf_h, ssrc, sdst, acc0, stream);
    run_conv(bf_in, rp_b, cs_b, W0b, as0b, ad0b, Wt, buf_h, ssrc, sdst, acc0, stream);
    leaky_bf16_kernel<<<nf4_blocks, 256, 0, stream>>>(acc0, bf_in);  // acc0 in-place + bf16

    // ---- layer 1 ----
    bias_init_kernel<<<nf_blocks, 256, 0, stream>>>(b1a, b1b, acc1);
    run_conv(bf_in, rp_a, cs_a, W1a, as1a, ad1a, Wt, buf_h, ssrc, sdst, acc1, stream);
    run_conv(bf_in, rp_b, cs_b, W1b, as1b, ad1b, Wt, buf_h, ssrc, sdst, acc1, stream);

    // ---- output projection ----
    convert_bf16_kernel<<<nf4_blocks, 256, 0, stream>>>(acc1, bf_in, (int)NF);
    wt_kernel<<<NC, 256, 0, stream>>>(Wout, Wt, NC);
    dim3 ogrid((N_NODES + 127) / 128, (NC + 127) / 128);
    mfma_gemm_bt<<<ogrid, 256, 0, stream>>>(bf_in, Wt, out, bout, N_NODES, NC);
}

// Round 5
// 833.258 us; speedup vs baseline: 2.0016x; 1.0690x over previous
//
#include <hip/hip_runtime.h>
#include <math.h>

#define N_NODES 50000
#define E_EDGES 250000
#define HD 256          // H * D
#define NH 4
#define DH 64
#define NC 153
#define KDIM 256        // all GEMMs have K = 256

// ---------- fp32 -> bf16 round-to-nearest-even ----------
__device__ __forceinline__ unsigned short f2bf(float f) {
    unsigned u = __float_as_uint(f);
    u = u + 0x7FFFu + ((u >> 16) & 1u);
    return (unsigned short)(u >> 16);
}

// ================= bf16 MFMA GEMM: C[M,Nc] = A[M,K] @ BT[Nc,K]^T (+bias) =========
typedef __attribute__((ext_vector_type(8))) short bf16x8;
typedef __attribute__((ext_vector_type(4))) float f32x4;
#define LDT 40

__global__ __launch_bounds__(256) void mfma_gemm_bt(
        const unsigned short* __restrict__ A, const unsigned short* __restrict__ BT,
        float* __restrict__ C, const float* __restrict__ bias, int M, int Nc) {
    __shared__ unsigned short As[128 * LDT];
    __shared__ unsigned short Bs[128 * LDT];
    const int tid = threadIdx.x;
    const int lane = tid & 63;
    const int wave = tid >> 6;
    const int wm = (wave & 1) * 64;
    const int wn = (wave >> 1) * 64;
    const int row0 = blockIdx.x * 128;
    const int col0 = blockIdx.y * 128;
    const int quad = lane >> 4;
    const int l16 = lane & 15;

    f32x4 acc[4][4];
    #pragma unroll
    for (int i = 0; i < 4; i++)
        #pragma unroll
        for (int j = 0; j < 4; j++) acc[i][j] = (f32x4)0.f;

    const int s_row = tid >> 2;
    const int s_cg  = (tid & 3) * 8;

    for (int k0 = 0; k0 < KDIM; k0 += 32) {
        #pragma unroll
        for (int h = 0; h < 2; h++) {
            const int r = s_row + h * 64;
            const int gr = row0 + r;
            bf16x8 va = (bf16x8)0;
            if (gr < M) va = *(const bf16x8*)&A[(size_t)gr * KDIM + k0 + s_cg];
            *(bf16x8*)&As[r * LDT + s_cg] = va;
            const int gn = col0 + r;
            bf16x8 vb = (bf16x8)0;
            if (gn < Nc) vb = *(const bf16x8*)&BT[(size_t)gn * KDIM + k0 + s_cg];
            *(bf16x8*)&Bs[r * LDT + s_cg] = vb;
        }
        __syncthreads();

        bf16x8 af[4], bfr[4];
        #pragma unroll
        for (int t = 0; t < 4; t++) {
            af[t]  = *(const bf16x8*)&As[(wm + t * 16 + l16) * LDT + quad * 8];
            bfr[t] = *(const bf16x8*)&Bs[(wn + t * 16 + l16) * LDT + quad * 8];
        }
        #pragma unroll
        for (int mt = 0; mt < 4; mt++)
            #pragma unroll
            for (int nt = 0; nt < 4; nt++)
                acc[mt][nt] = __builtin_amdgcn_mfma_f32_16x16x32_bf16(
                                  af[mt], bfr[nt], acc[mt][nt], 0, 0, 0);
        __syncthreads();
    }

    #pragma unroll
    for (int mt = 0; mt < 4; mt++) {
        #pragma unroll
        for (int nt = 0; nt < 4; nt++) {
            const int n = col0 + wn + nt * 16 + l16;
            if (n >= Nc) continue;
            const float bv = bias ? bias[n] : 0.f;
            #pragma unroll
            for (int r = 0; r < 4; r++) {
                const int m = row0 + wm + mt * 16 + quad * 4 + r;
                if (m < M) C[(size_t)m * Nc + n] = acc[mt][nt][r] + bv;
            }
        }
    }
}

// ---------- fp32 -> bf16 conversion (vectorized) ----------
__global__ __launch_bounds__(256) void convert_bf16_kernel(
        const float* __restrict__ in, unsigned short* __restrict__ out, int n) {
    const int i = (blockIdx.x * 256 + threadIdx.x) * 4;
    if (i + 3 < n) {
        const float4 v = *(const float4*)&in[i];
        ushort4 o;
        o.x = f2bf(v.x); o.y = f2bf(v.y); o.z = f2bf(v.z); o.w = f2bf(v.w);
        *(ushort4*)&out[i] = o;
    } else {
        for (int j = i; j < n; j++) out[j] = f2bf(in[j]);
    }
}

// ---------- fused leaky-relu (0.01) in-place + bf16 copy ----------
__global__ __launch_bounds__(256) void leaky_bf16_kernel(
        float* __restrict__ x, unsigned short* __restrict__ out) {
    const int i = (blockIdx.x * 256 + threadIdx.x) * 4;
    if (i >= N_NODES * HD) return;
    float4 v = *(float4*)&x[i];
    v.x = (v.x >= 0.f) ? v.x : 0.01f * v.x;
    v.y = (v.y >= 0.f) ? v.y : 0.01f * v.y;
    v.z = (v.z >= 0.f) ? v.z : 0.01f * v.z;
    v.w = (v.w >= 0.f) ? v.w : 0.01f * v.w;
    *(float4*)&x[i] = v;
    ushort4 o;
    o.x = f2bf(v.x); o.y = f2bf(v.y); o.z = f2bf(v.z); o.w = f2bf(v.w);
    *(ushort4*)&out[i] = o;
}

// ---------- weight transpose+convert: W[K,Nc] fp32 -> Wt[Nc,K] bf16 ----------
__global__ __launch_bounds__(256) void wt_kernel(
        const float* __restrict__ W, unsigned short* __restrict__ Wt, int Nc) {
    const int idx = blockIdx.x * 256 + threadIdx.x;
    const int n = idx >> 8, k = idx & 255;
    if (n < Nc) Wt[idx] = f2bf(W[(size_t)k * Nc + n]);
}

// ---------- CSR construction ----------
__global__ __launch_bounds__(256) void zero_int_kernel(int* __restrict__ p, int n) {
    const int i = blockIdx.x * 256 + threadIdx.x;
    if (i < n) p[i] = 0;
}

__global__ __launch_bounds__(256) void hist_kernel(
        const int* __restrict__ ei, int* __restrict__ deg) {
    const int e = blockIdx.x * 256 + threadIdx.x;
    if (e < E_EDGES) atomicAdd(&deg[ei[E_EDGES + e]], 1);
}

__global__ __launch_bounds__(1024) void scan_local_kernel(
        const int* __restrict__ deg, int* __restrict__ excl,
        int* __restrict__ bsums, int n) {
    __shared__ int wsum[16];
    const int i = blockIdx.x * 1024 + threadIdx.x;
    const int lane = threadIdx.x & 63;
    const int wid = threadIdx.x >> 6;
    const int v = (i < n) ? deg[i] : 0;
    int s = v;
    #pragma unroll
    for (int off = 1; off < 64; off <<= 1) {
        const int t = __shfl_up(s, off);
        if (lane >= off) s += t;
    }
    if (lane == 63) wsum[wid] = s;
    __syncthreads();
    if (wid == 0) {
        int wv = (lane < 16) ? wsum[lane] : 0;
        #pragma unroll
        for (int off = 1; off < 16; off <<= 1) {
            const int t = __shfl_up(wv, off);
            if (lane >= off) wv += t;
        }
        if (lane < 16) wsum[lane] = wv;
    }
    __syncthreads();
    const int woff = (wid > 0) ? wsum[wid - 1] : 0;
    if (i < n) excl[i] = s - v + woff;
    if (threadIdx.x == 1023) bsums[blockIdx.x] = wsum[15];
}

__global__ __launch_bounds__(64) void scan_bsums_kernel(
        int* __restrict__ bsums, int* __restrict__ row_ptr, int nb, int n) {
    const int lane = threadIdx.x;
    const int v = (lane < nb) ? bsums[lane] : 0;
    int s = v;
    #pragma unroll
    for (int off = 1; off < 64; off <<= 1) {
        const int t = __shfl_up(s, off);
        if (lane >= off) s += t;
    }
    if (lane < nb) bsums[lane] = s - v;
    if (lane == 63) row_ptr[n] = s;
}

__global__ __launch_bounds__(256) void scan_add_kernel(
        const int* __restrict__ excl, const int* __restrict__ bsums,
        int* __restrict__ row_ptr, int* __restrict__ cursor, int n) {
    const int i = blockIdx.x * 256 + threadIdx.x;
    if (i >= n) return;
    const int v = excl[i] + bsums[i >> 10];
    row_ptr[i] = v;
    cursor[i]  = v;
}

__global__ __launch_bounds__(256) void scatter_kernel(
        const int* __restrict__ ei, int* __restrict__ cursor,
        int* __restrict__ col_src, int* __restrict__ col_dst) {
    const int e = blockIdx.x * 256 + threadIdx.x;
    if (e >= E_EDGES) return;
    const int src = ei[e], dst = ei[E_EDGES + e];
    const int pos = atomicAdd(&cursor[dst], 1);
    col_src[pos] = src;
    col_dst[pos] = dst;
}

// ---------- per-node attention scores ----------
__global__ __launch_bounds__(256) void scores_kernel(
        const float* __restrict__ h, const float* __restrict__ asrc,
        const float* __restrict__ adst, float* __restrict__ ssrc,
        float* __restrict__ sdst) {
    const int node = blockIdx.x * 4 + (threadIdx.x >> 6);
    const int lane = threadIdx.x & 63;
    if (node >= N_NODES) return;
    const float* hp = h + (size_t)node * HD;
    float rs[NH], rd[NH];
    #pragma unroll
    for (int hh = 0; hh < NH; hh++) {
        float v = hp[hh * DH + lane];
        rs[hh] = v * asrc[hh * DH + lane];
        rd[hh] = v * adst[hh * DH + lane];
    }
    #pragma unroll
    for (int off = 32; off > 0; off >>= 1) {
        #pragma unroll
        for (int hh = 0; hh < NH; hh++) {
            rs[hh] += __shfl_xor(rs[hh], off);
            rd[hh] += __shfl_xor(rd[hh], off);
        }
    }
    if (lane < NH) {
        ssrc[node * NH + lane] = rs[lane];
        sdst[node * NH + lane] = rd[lane];
    }
}

// ---------- S1: per (node,head) thread computes m and 1/(z+eps) over CSR ----------
__global__ __launch_bounds__(256) void seg_mz_kernel(
        const int* __restrict__ rp, const int* __restrict__ cs,
        const float* __restrict__ ssrc, const float* __restrict__ sdst,
        float* __restrict__ mbuf, float* __restrict__ zrbuf) {
    const int t = blockIdx.x * 256 + threadIdx.x;
    if (t >= N_NODES * NH) return;
    const int node = t >> 2, hh = t & 3;
    const int beg = rp[node], end = rp[node + 1];
    const float sd = sdst[t];
    float m = -INFINITY;
    for (int e = beg; e < end; e++) {
        float s = ssrc[cs[e] * NH + hh] + sd;
        s = (s >= 0.f) ? s : 0.2f * s;
        m = fmaxf(m, s);
    }
    float z = 0.f;
    for (int e = beg; e < end; e++) {
        float s = ssrc[cs[e] * NH + hh] + sd;
        s = (s >= 0.f) ? s : 0.2f * s;
        z += expf(s - m);
    }
    mbuf[t]  = m;
    zrbuf[t] = 1.f / (z + 1e-16f);
}

// ---------- S2: per (edge,head) thread computes alpha in CSR order ----------
__global__ __launch_bounds__(256) void alpha_kernel(
        const int* __restrict__ cs, const int* __restrict__ cd,
        const float* __restrict__ ssrc, const float* __restrict__ sdst,
        const float* __restrict__ mbuf, const float* __restrict__ zrbuf,
        float* __restrict__ ebuf) {
    const int t = blockIdx.x * 256 + threadIdx.x;
    if (t >= E_EDGES * NH) return;
    const int pos = t >> 2, hh = t & 3;
    const int src = cs[pos], dst = cd[pos];
    float s = ssrc[src * NH + hh] + sdst[dst * NH + hh];
    s = (s >= 0.f) ? s : 0.2f * s;
    ebuf[t] = expf(s - mbuf[dst * NH + hh]) * zrbuf[dst * NH + hh];
}

// ---------- S3: streaming aggregation, wave per node, float4 per lane ----------
__global__ __launch_bounds__(256) void aggregate_csr_kernel(
        const int* __restrict__ rp, const int* __restrict__ cs,
        const float* __restrict__ hbuf, const float* __restrict__ ebuf,
        float* __restrict__ acc) {
    const int node = blockIdx.x * 4 + (threadIdx.x >> 6);
    const int lane = threadIdx.x & 63;
    if (node >= N_NODES) return;
    const int beg = rp[node], end = rp[node + 1];
    const int hh = lane >> 4;            // head owning this lane's float4

    float4 a = make_float4(0.f, 0.f, 0.f, 0.f);
    for (int e = beg; e < end; e++) {
        const int src = cs[e];
        const float al = ebuf[e * NH + hh];
        const float4 hv = *(const float4*)&hbuf[(size_t)src * HD + lane * 4];
        a.x = fmaf(al, hv.x, a.x);
        a.y = fmaf(al, hv.y, a.y);
        a.z = fmaf(al, hv.z, a.z);
        a.w = fmaf(al, hv.w, a.w);
    }
    float4* op = (float4*)&acc[(size_t)node * HD + lane * 4];
    float4 o = *op;
    o.x += a.x; o.y += a.y; o.z += a.z; o.w += a.w;
    *op = o;
}

// ---------- acc init with summed biases ----------
__global__ __launch_bounds__(256) void bias_init_kernel(
        const float* __restrict__ b1, const float* __restrict__ b2,
        float* __restrict__ acc) {
    const int idx = blockIdx.x * 256 + threadIdx.x;
    if (idx >= N_NODES * HD) return;
    const int c = idx & (HD - 1);
    acc[idx] = b1[c] + b2[c];
}

// ---------- host-side helpers ----------
static void run_conv(const unsigned short* a_bf, const int* row_ptr,
                     const int* col_src, const int* col_dst,
                     const float* W, const float* asrc, const float* adst,
                     unsigned short* Wt, float* buf_h, float* ssrc, float* sdst,
                     float* mbuf, float* zrbuf, float* ebuf, float* acc,
                     hipStream_t stream) {
    wt_kernel<<<HD, 256, 0, stream>>>(W, Wt, HD);
    dim3 ggrid((N_NODES + 127) / 128, (HD + 127) / 128);
    mfma_gemm_bt<<<ggrid, 256, 0, stream>>>(a_bf, Wt, buf_h, nullptr, N_NODES, HD);
    scores_kernel<<<(N_NODES + 3) / 4, 256, 0, stream>>>(buf_h, asrc, adst, ssrc, sdst);
    seg_mz_kernel<<<(N_NODES * NH + 255) / 256, 256, 0, stream>>>(
        row_ptr, col_src, ssrc, sdst, mbuf, zrbuf);
    alpha_kernel<<<(E_EDGES * NH + 255) / 256, 256, 0, stream>>>(
        col_src, col_dst, ssrc, sdst, mbuf, zrbuf, ebuf);
    aggregate_csr_kernel<<<(N_NODES + 3) / 4, 256, 0, stream>>>(
        row_ptr, col_src, buf_h, ebuf, acc);
}

static void build_csr(const int* ei, int* deg, int* cursor, int* row_ptr,
                      int* col_src, int* col_dst, int* excl, int* bsums,
                      hipStream_t stream) {
    const int nb  = (N_NODES + 255) / 256;
    const int eb  = (E_EDGES + 255) / 256;
    const int sb  = (N_NODES + 1023) / 1024;
    zero_int_kernel<<<nb, 256, 0, stream>>>(deg, N_NODES);
    hist_kernel<<<eb, 256, 0, stream>>>(ei, deg);
    scan_local_kernel<<<sb, 1024, 0, stream>>>(deg, excl, bsums, N_NODES);
    scan_bsums_kernel<<<1, 64, 0, stream>>>(bsums, row_ptr, sb, N_NODES);
    scan_add_kernel<<<nb, 256, 0, stream>>>(excl, bsums, row_ptr, cursor, N_NODES);
    scatter_kernel<<<eb, 256, 0, stream>>>(ei, cursor, col_src, col_dst);
}

extern "C" void kernel_launch(void* const* d_in, const int* in_sizes, int n_in,
                              void* d_out, int out_size, void* d_ws, size_t ws_size,
                              hipStream_t stream) {
    const float* x    = (const float*)d_in[0];
    const int*   ei_a = (const int*)d_in[1];
    const int*   ei_b = (const int*)d_in[2];
    const float* W0a = (const float*)d_in[3];
    const float* as0a = (const float*)d_in[4];
    const float* ad0a = (const float*)d_in[5];
    const float* b0a = (const float*)d_in[6];
    const float* W0b = (const float*)d_in[7];
    const float* as0b = (const float*)d_in[8];
    const float* ad0b = (const float*)d_in[9];
    const float* b0b = (const float*)d_in[10];
    const float* W1a = (const float*)d_in[11];
    const float* as1a = (const float*)d_in[12];
    const float* ad1a = (const float*)d_in[13];
    const float* b1a = (const float*)d_in[14];
    const float* W1b = (const float*)d_in[15];
    const float* as1b = (const float*)d_in[16];
    const float* ad1b = (const float*)d_in[17];
    const float* b1b = (const float*)d_in[18];
    const float* Wout = (const float*)d_in[19];
    const float* bout = (const float*)d_in[20];
    float* out = (float*)d_out;

    // workspace carve
    float* ws = (float*)d_ws;
    const size_t NF = (size_t)N_NODES * HD;   // 12.8M
    float* buf_h  = ws;                         // NF
    float* acc0   = buf_h + NF;                 // NF
    float* acc1   = acc0 + NF;                  // NF
    unsigned short* bf_in = (unsigned short*)(acc1 + NF);       // NF ushort
    unsigned short* Wt    = bf_in + NF;                         // 256*256 ushort
    float* ssrc   = (float*)(Wt + (size_t)KDIM * KDIM);         // N*4
    float* sdst   = ssrc + (size_t)N_NODES * NH;                // N*4
    float* mbuf   = sdst + (size_t)N_NODES * NH;                // N*4
    float* zrbuf  = mbuf + (size_t)N_NODES * NH;                // N*4
    float* ebuf   = zrbuf + (size_t)N_NODES * NH;               // E*4
    int*   ibase  = (int*)(ebuf + (size_t)E_EDGES * NH);
    int* deg     = ibase;
    int* cursor  = deg + N_NODES;
    int* rp_a    = cursor + N_NODES;
    int* cs_a    = rp_a + N_NODES + 1;
    int* cd_a    = cs_a + E_EDGES;
    int* rp_b    = cd_a + E_EDGES;
    int* cs_b    = rp_b + N_NODES + 1;
    int* cd_b    = cs_b + E_EDGES;
    int* excl    = cd_b + E_EDGES;
    int* bsums   = excl + N_NODES;

    const int nf_blocks  = (int)((NF + 255) / 256);
    const int nf4_blocks = (int)((NF / 4 + 255) / 256);

    // ---- CSR for both edge types (reused by both layers) ----
    build_csr(ei_a, deg, cursor, rp_a, cs_a, cd_a, excl, bsums, stream);
    build_csr(ei_b, deg, cursor, rp_b, cs_b, cd_b, excl, bsums, stream);

    // ---- layer 0 ----
    convert_bf16_kernel<<<nf4_blocks, 256, 0, stream>>>(x, bf_in, (int)NF);
    bias_init_kernel<<<nf_blocks, 256, 0, stream>>>(b0a, b0b, acc0);
    run_conv(bf_in, rp_a, cs_a, cd_a, W0a, as0a, ad0a, Wt, buf_h, ssrc, sdst,
             mbuf, zrbuf, ebuf, acc0, stream);
    run_conv(bf_in, rp_b, cs_b, cd_b, W0b, as0b, ad0b, Wt, buf_h, ssrc, sdst,
             mbuf, zrbuf, ebuf, acc0, stream);
    leaky_bf16_kernel<<<nf4_blocks, 256, 0, stream>>>(acc0, bf_in);

    // ---- layer 1 ----
    bias_init_kernel<<<nf_blocks, 256, 0, stream>>>(b1a, b1b, acc1);
    run_conv(bf_in, rp_a, cs_a, cd_a, W1a, as1a, ad1a, Wt, buf_h, ssrc, sdst,
             mbuf, zrbuf, ebuf, acc1, stream);
    run_conv(bf_in, rp_b, cs_b, cd_b, W1b, as1b, ad1b, Wt, buf_h, ssrc, sdst,
             mbuf, zrbuf, ebuf, acc1, stream);

    // ---- output projection ----
    convert_bf16_kernel<<<nf4_blocks, 256, 0, stream>>>(acc1, bf_in, (int)NF);
    wt_kernel<<<NC, 256, 0, stream>>>(Wout, Wt, NC);
    dim3 ogrid((N_NODES + 127) / 128, (NC + 127) / 128);
    mfma_gemm_bt<<<ogrid, 256, 0, stream>>>(bf_in, Wt, out, bout, N_NODES, NC);
}

// Round 6
// 732.780 us; speedup vs baseline: 2.2760x; 1.1371x over previous
//
#include <hip/hip_runtime.h>
#include <math.h>

#define N_NODES 50000
#define E_EDGES 250000
#define HD 256          // H * D
#define NH 4
#define DH 64
#define NC 153
#define KDIM 256        // all GEMMs have K = 256

// ---------- fp32 <-> bf16 ----------
__device__ __forceinline__ unsigned short f2bf(float f) {
    unsigned u = __float_as_uint(f);
    u = u + 0x7FFFu + ((u >> 16) & 1u);
    return (unsigned short)(u >> 16);
}
__device__ __forceinline__ float bf2f(unsigned short b) {
    return __uint_as_float(((unsigned)b) << 16);
}

// ================= bf16 MFMA GEMM: C = A[M,K] @ BT[Nc,K]^T (+bias) =========
// Writes fp32 (Cf, with optional bias) and/or bf16 (Cbf).
typedef __attribute__((ext_vector_type(8))) short bf16x8;
typedef __attribute__((ext_vector_type(4))) float f32x4;
#define LDT 40

__global__ __launch_bounds__(256) void mfma_gemm_bt(
        const unsigned short* __restrict__ A, const unsigned short* __restrict__ BT,
        float* __restrict__ Cf, unsigned short* __restrict__ Cbf,
        const float* __restrict__ bias, int M, int Nc) {
    __shared__ unsigned short As[128 * LDT];
    __shared__ unsigned short Bs[128 * LDT];
    const int tid = threadIdx.x;
    const int lane = tid & 63;
    const int wave = tid >> 6;
    const int wm = (wave & 1) * 64;
    const int wn = (wave >> 1) * 64;
    const int row0 = blockIdx.x * 128;
    const int col0 = blockIdx.y * 128;
    const int quad = lane >> 4;
    const int l16 = lane & 15;

    f32x4 acc[4][4];
    #pragma unroll
    for (int i = 0; i < 4; i++)
        #pragma unroll
        for (int j = 0; j < 4; j++) acc[i][j] = (f32x4)0.f;

    const int s_row = tid >> 2;
    const int s_cg  = (tid & 3) * 8;

    for (int k0 = 0; k0 < KDIM; k0 += 32) {
        #pragma unroll
        for (int h = 0; h < 2; h++) {
            const int r = s_row + h * 64;
            const int gr = row0 + r;
            bf16x8 va = (bf16x8)0;
            if (gr < M) va = *(const bf16x8*)&A[(size_t)gr * KDIM + k0 + s_cg];
            *(bf16x8*)&As[r * LDT + s_cg] = va;
            const int gn = col0 + r;
            bf16x8 vb = (bf16x8)0;
            if (gn < Nc) vb = *(const bf16x8*)&BT[(size_t)gn * KDIM + k0 + s_cg];
            *(bf16x8*)&Bs[r * LDT + s_cg] = vb;
        }
        __syncthreads();

        bf16x8 af[4], bfr[4];
        #pragma unroll
        for (int t = 0; t < 4; t++) {
            af[t]  = *(const bf16x8*)&As[(wm + t * 16 + l16) * LDT + quad * 8];
            bfr[t] = *(const bf16x8*)&Bs[(wn + t * 16 + l16) * LDT + quad * 8];
        }
        #pragma unroll
        for (int mt = 0; mt < 4; mt++)
            #pragma unroll
            for (int nt = 0; nt < 4; nt++)
                acc[mt][nt] = __builtin_amdgcn_mfma_f32_16x16x32_bf16(
                                  af[mt], bfr[nt], acc[mt][nt], 0, 0, 0);
        __syncthreads();
    }

    // epilogue: D col = lane&15, row = quad*4 + reg
    #pragma unroll
    for (int mt = 0; mt < 4; mt++) {
        #pragma unroll
        for (int nt = 0; nt < 4; nt++) {
            const int n = col0 + wn + nt * 16 + l16;
            if (n >= Nc) continue;
            const float bv = bias ? bias[n] : 0.f;
            #pragma unroll
            for (int r = 0; r < 4; r++) {
                const int m = row0 + wm + mt * 16 + quad * 4 + r;
                if (m < M) {
                    const float v = acc[mt][nt][r] + bv;
                    if (Cf)  Cf[(size_t)m * Nc + n] = v;
                    if (Cbf) Cbf[(size_t)m * Nc + n] = f2bf(v);
                }
            }
        }
    }
}

// ---------- fp32 -> bf16 conversion (vectorized) ----------
__global__ __launch_bounds__(256) void convert_bf16_kernel(
        const float* __restrict__ in, unsigned short* __restrict__ out, int n) {
    const int i = (blockIdx.x * 256 + threadIdx.x) * 4;
    if (i + 3 < n) {
        const float4 v = *(const float4*)&in[i];
        ushort4 o;
        o.x = f2bf(v.x); o.y = f2bf(v.y); o.z = f2bf(v.z); o.w = f2bf(v.w);
        *(ushort4*)&out[i] = o;
    } else {
        for (int j = i; j < n; j++) out[j] = f2bf(in[j]);
    }
}

// ---------- fused leaky-relu (0.01) in-place + bf16 copy ----------
__global__ __launch_bounds__(256) void leaky_bf16_kernel(
        float* __restrict__ x, unsigned short* __restrict__ out) {
    const int i = (blockIdx.x * 256 + threadIdx.x) * 4;
    if (i >= N_NODES * HD) return;
    float4 v = *(float4*)&x[i];
    v.x = (v.x >= 0.f) ? v.x : 0.01f * v.x;
    v.y = (v.y >= 0.f) ? v.y : 0.01f * v.y;
    v.z = (v.z >= 0.f) ? v.z : 0.01f * v.z;
    v.w = (v.w >= 0.f) ? v.w : 0.01f * v.w;
    *(float4*)&x[i] = v;
    ushort4 o;
    o.x = f2bf(v.x); o.y = f2bf(v.y); o.z = f2bf(v.z); o.w = f2bf(v.w);
    *(ushort4*)&out[i] = o;
}

// ---------- weight transpose+convert: W[K,Nc] fp32 -> Wt[Nc,K] bf16 ----------
__global__ __launch_bounds__(256) void wt_kernel(
        const float* __restrict__ W, unsigned short* __restrict__ Wt, int Nc) {
    const int idx = blockIdx.x * 256 + threadIdx.x;
    const int n = idx >> 8, k = idx & 255;
    if (n < Nc) Wt[idx] = f2bf(W[(size_t)k * Nc + n]);
}

// ---------- CSR construction ----------
__global__ __launch_bounds__(256) void zero_int_kernel(int* __restrict__ p, int n) {
    const int i = blockIdx.x * 256 + threadIdx.x;
    if (i < n) p[i] = 0;
}

__global__ __launch_bounds__(256) void hist_kernel(
        const int* __restrict__ ei, int* __restrict__ deg) {
    const int e = blockIdx.x * 256 + threadIdx.x;
    if (e < E_EDGES) atomicAdd(&deg[ei[E_EDGES + e]], 1);
}

__global__ __launch_bounds__(1024) void scan_local_kernel(
        const int* __restrict__ deg, int* __restrict__ excl,
        int* __restrict__ bsums, int n) {
    __shared__ int wsum[16];
    const int i = blockIdx.x * 1024 + threadIdx.x;
    const int lane = threadIdx.x & 63;
    const int wid = threadIdx.x >> 6;
    const int v = (i < n) ? deg[i] : 0;
    int s = v;
    #pragma unroll
    for (int off = 1; off < 64; off <<= 1) {
        const int t = __shfl_up(s, off);
        if (lane >= off) s += t;
    }
    if (lane == 63) wsum[wid] = s;
    __syncthreads();
    if (wid == 0) {
        int wv = (lane < 16) ? wsum[lane] : 0;
        #pragma unroll
        for (int off = 1; off < 16; off <<= 1) {
            const int t = __shfl_up(wv, off);
            if (lane >= off) wv += t;
        }
        if (lane < 16) wsum[lane] = wv;
    }
    __syncthreads();
    const int woff = (wid > 0) ? wsum[wid - 1] : 0;
    if (i < n) excl[i] = s - v + woff;
    if (threadIdx.x == 1023) bsums[blockIdx.x] = wsum[15];
}

__global__ __launch_bounds__(64) void scan_bsums_kernel(
        int* __restrict__ bsums, int* __restrict__ row_ptr, int nb, int n) {
    const int lane = threadIdx.x;
    const int v = (lane < nb) ? bsums[lane] : 0;
    int s = v;
    #pragma unroll
    for (int off = 1; off < 64; off <<= 1) {
        const int t = __shfl_up(s, off);
        if (lane >= off) s += t;
    }
    if (lane < nb) bsums[lane] = s - v;
    if (lane == 63) row_ptr[n] = s;
}

__global__ __launch_bounds__(256) void scan_add_kernel(
        const int* __restrict__ excl, const int* __restrict__ bsums,
        int* __restrict__ row_ptr, int* __restrict__ cursor, int n) {
    const int i = blockIdx.x * 256 + threadIdx.x;
    if (i >= n) return;
    const int v = excl[i] + bsums[i >> 10];
    row_ptr[i] = v;
    cursor[i]  = v;
}

__global__ __launch_bounds__(256) void scatter_kernel(
        const int* __restrict__ ei, int* __restrict__ cursor,
        int* __restrict__ col_src, int* __restrict__ col_dst) {
    const int e = blockIdx.x * 256 + threadIdx.x;
    if (e >= E_EDGES) return;
    const int src = ei[e], dst = ei[E_EDGES + e];
    const int pos = atomicAdd(&cursor[dst], 1);
    col_src[pos] = src;
    col_dst[pos] = dst;
}

// ---------- per-node attention scores (bf16 h, lane owns 4 contiguous elems) ----------
__global__ __launch_bounds__(256) void scores_kernel(
        const unsigned short* __restrict__ hbf, const float* __restrict__ asrc,
        const float* __restrict__ adst, float* __restrict__ ssrc,
        float* __restrict__ sdst) {
    const int node = blockIdx.x * 4 + (threadIdx.x >> 6);
    const int lane = threadIdx.x & 63;
    if (node >= N_NODES) return;
    const ushort4 hv = *(const ushort4*)&hbf[(size_t)node * HD + lane * 4];
    const float4 av = *(const float4*)&asrc[lane * 4];
    const float4 dv = *(const float4*)&adst[lane * 4];
    const float h0 = bf2f(hv.x), h1 = bf2f(hv.y), h2 = bf2f(hv.z), h3 = bf2f(hv.w);
    float rs = h0 * av.x + h1 * av.y + h2 * av.z + h3 * av.w;
    float rd = h0 * dv.x + h1 * dv.y + h2 * dv.z + h3 * dv.w;
    #pragma unroll
    for (int off = 1; off < 16; off <<= 1) {
        rs += __shfl_xor(rs, off);
        rd += __shfl_xor(rd, off);
    }
    if ((lane & 15) == 0) {
        const int hh = lane >> 4;
        ssrc[node * NH + hh] = rs;
        sdst[node * NH + hh] = rd;
    }
}

// ---------- S1: per (node,head) thread computes m and 1/(z+eps) over CSR ----------
__global__ __launch_bounds__(256) void seg_mz_kernel(
        const int* __restrict__ rp, const int* __restrict__ cs,
        const float* __restrict__ ssrc, const float* __restrict__ sdst,
        float* __restrict__ mbuf, float* __restrict__ zrbuf) {
    const int t = blockIdx.x * 256 + threadIdx.x;
    if (t >= N_NODES * NH) return;
    const int node = t >> 2, hh = t & 3;
    const int beg = rp[node], end = rp[node + 1];
    const float sd = sdst[t];
    float m = -INFINITY;
    for (int e = beg; e < end; e++) {
        float s = ssrc[cs[e] * NH + hh] + sd;
        s = (s >= 0.f) ? s : 0.2f * s;
        m = fmaxf(m, s);
    }
    float z = 0.f;
    for (int e = beg; e < end; e++) {
        float s = ssrc[cs[e] * NH + hh] + sd;
        s = (s >= 0.f) ? s : 0.2f * s;
        z += expf(s - m);
    }
    mbuf[t]  = m;
    zrbuf[t] = 1.f / (z + 1e-16f);
}

// ---------- S2: per (edge,head) thread computes alpha in CSR order ----------
__global__ __launch_bounds__(256) void alpha_kernel(
        const int* __restrict__ cs, const int* __restrict__ cd,
        const float* __restrict__ ssrc, const float* __restrict__ sdst,
        const float* __restrict__ mbuf, const float* __restrict__ zrbuf,
        float* __restrict__ ebuf) {
    const int t = blockIdx.x * 256 + threadIdx.x;
    if (t >= E_EDGES * NH) return;
    const int pos = t >> 2, hh = t & 3;
    const int src = cs[pos], dst = cd[pos];
    float s = ssrc[src * NH + hh] + sdst[dst * NH + hh];
    s = (s >= 0.f) ? s : 0.2f * s;
    ebuf[t] = expf(s - mbuf[dst * NH + hh]) * zrbuf[dst * NH + hh];
}

// ---------- S3: streaming aggregation over bf16 h, wave per node ----------
__global__ __launch_bounds__(256) void aggregate_csr_kernel(
        const int* __restrict__ rp, const int* __restrict__ cs,
        const unsigned short* __restrict__ hbf, const float* __restrict__ ebuf,
        float* __restrict__ acc) {
    const int node = blockIdx.x * 4 + (threadIdx.x >> 6);
    const int lane = threadIdx.x & 63;
    if (node >= N_NODES) return;
    const int beg = rp[node], end = rp[node + 1];
    const int hh = lane >> 4;            // head owning this lane's 4 elems

    float4 a = make_float4(0.f, 0.f, 0.f, 0.f);
    for (int e = beg; e < end; e++) {
        const int src = cs[e];
        const float al = ebuf[e * NH + hh];
        const ushort4 hv = *(const ushort4*)&hbf[(size_t)src * HD + lane * 4];
        a.x = fmaf(al, bf2f(hv.x), a.x);
        a.y = fmaf(al, bf2f(hv.y), a.y);
        a.z = fmaf(al, bf2f(hv.z), a.z);
        a.w = fmaf(al, bf2f(hv.w), a.w);
    }
    float4* op = (float4*)&acc[(size_t)node * HD + lane * 4];
    float4 o = *op;
    o.x += a.x; o.y += a.y; o.z += a.z; o.w += a.w;
    *op = o;
}

// ---------- acc init with summed biases ----------
__global__ __launch_bounds__(256) void bias_init_kernel(
        const float* __restrict__ b1, const float* __restrict__ b2,
        float* __restrict__ acc) {
    const int idx = blockIdx.x * 256 + threadIdx.x;
    if (idx >= N_NODES * HD) return;
    const int c = idx & (HD - 1);
    acc[idx] = b1[c] + b2[c];
}

// ---------- host-side helpers ----------
static void run_conv(const unsigned short* a_bf, const int* row_ptr,
                     const int* col_src, const int* col_dst,
                     const float* W, const float* asrc, const float* adst,
                     unsigned short* Wt, unsigned short* h_bf,
                     float* ssrc, float* sdst,
                     float* mbuf, float* zrbuf, float* ebuf, float* acc,
                     hipStream_t stream) {
    wt_kernel<<<HD, 256, 0, stream>>>(W, Wt, HD);
    dim3 ggrid((N_NODES + 127) / 128, (HD + 127) / 128);
    mfma_gemm_bt<<<ggrid, 256, 0, stream>>>(a_bf, Wt, nullptr, h_bf, nullptr,
                                            N_NODES, HD);
    scores_kernel<<<(N_NODES + 3) / 4, 256, 0, stream>>>(h_bf, asrc, adst, ssrc, sdst);
    seg_mz_kernel<<<(N_NODES * NH + 255) / 256, 256, 0, stream>>>(
        row_ptr, col_src, ssrc, sdst, mbuf, zrbuf);
    alpha_kernel<<<(E_EDGES * NH + 255) / 256, 256, 0, stream>>>(
        col_src, col_dst, ssrc, sdst, mbuf, zrbuf, ebuf);
    aggregate_csr_kernel<<<(N_NODES + 3) / 4, 256, 0, stream>>>(
        row_ptr, col_src, h_bf, ebuf, acc);
}

static void build_csr(const int* ei, int* deg, int* cursor, int* row_ptr,
                      int* col_src, int* col_dst, int* excl, int* bsums,
                      hipStream_t stream) {
    const int nb  = (N_NODES + 255) / 256;
    const int eb  = (E_EDGES + 255) / 256;
    const int sb  = (N_NODES + 1023) / 1024;
    zero_int_kernel<<<nb, 256, 0, stream>>>(deg, N_NODES);
    hist_kernel<<<eb, 256, 0, stream>>>(ei, deg);
    scan_local_kernel<<<sb, 1024, 0, stream>>>(deg, excl, bsums, N_NODES);
    scan_bsums_kernel<<<1, 64, 0, stream>>>(bsums, row_ptr, sb, N_NODES);
    scan_add_kernel<<<nb, 256, 0, stream>>>(excl, bsums, row_ptr, cursor, N_NODES);
    scatter_kernel<<<eb, 256, 0, stream>>>(ei, cursor, col_src, col_dst);
}

extern "C" void kernel_launch(void* const* d_in, const int* in_sizes, int n_in,
                              void* d_out, int out_size, void* d_ws, size_t ws_size,
                              hipStream_t stream) {
    const float* x    = (const float*)d_in[0];
    const int*   ei_a = (const int*)d_in[1];
    const int*   ei_b = (const int*)d_in[2];
    const float* W0a = (const float*)d_in[3];
    const float* as0a = (const float*)d_in[4];
    const float* ad0a = (const float*)d_in[5];
    const float* b0a = (const float*)d_in[6];
    const float* W0b = (const float*)d_in[7];
    const float* as0b = (const float*)d_in[8];
    const float* ad0b = (const float*)d_in[9];
    const float* b0b = (const float*)d_in[10];
    const float* W1a = (const float*)d_in[11];
    const float* as1a = (const float*)d_in[12];
    const float* ad1a = (const float*)d_in[13];
    const float* b1a = (const float*)d_in[14];
    const float* W1b = (const float*)d_in[15];
    const float* as1b = (const float*)d_in[16];
    const float* ad1b = (const float*)d_in[17];
    const float* b1b = (const float*)d_in[18];
    const float* Wout = (const float*)d_in[19];
    const float* bout = (const float*)d_in[20];
    float* out = (float*)d_out;

    // workspace carve
    float* ws = (float*)d_ws;
    const size_t NF = (size_t)N_NODES * HD;   // 12.8M
    float* acc0   = ws;                         // NF
    float* acc1   = acc0 + NF;                  // NF
    unsigned short* h_bf  = (unsigned short*)(acc1 + NF);       // NF ushort
    unsigned short* bf_in = h_bf + NF;                          // NF ushort
    unsigned short* Wt    = bf_in + NF;                         // 256*256 ushort
    float* ssrc   = (float*)(Wt + (size_t)KDIM * KDIM);         // N*4
    float* sdst   = ssrc + (size_t)N_NODES * NH;                // N*4
    float* mbuf   = sdst + (size_t)N_NODES * NH;                // N*4
    float* zrbuf  = mbuf + (size_t)N_NODES * NH;                // N*4
    float* ebuf   = zrbuf + (size_t)N_NODES * NH;               // E*4
    int*   ibase  = (int*)(ebuf + (size_t)E_EDGES * NH);
    int* deg     = ibase;
    int* cursor  = deg + N_NODES;
    int* rp_a    = cursor + N_NODES;
    int* cs_a    = rp_a + N_NODES + 1;
    int* cd_a    = cs_a + E_EDGES;
    int* rp_b    = cd_a + E_EDGES;
    int* cs_b    = rp_b + N_NODES + 1;
    int* cd_b    = cs_b + E_EDGES;
    int* excl    = cd_b + E_EDGES;
    int* bsums   = excl + N_NODES;

    const int nf_blocks  = (int)((NF + 255) / 256);
    const int nf4_blocks = (int)((NF / 4 + 255) / 256);

    // ---- CSR for both edge types (reused by both layers) ----
    build_csr(ei_a, deg, cursor, rp_a, cs_a, cd_a, excl, bsums, stream);
    build_csr(ei_b, deg, cursor, rp_b, cs_b, cd_b, excl, bsums, stream);

    // ---- layer 0 ----
    convert_bf16_kernel<<<nf4_blocks, 256, 0, stream>>>(x, bf_in, (int)NF);
    bias_init_kernel<<<nf_blocks, 256, 0, stream>>>(b0a, b0b, acc0);
    run_conv(bf_in, rp_a, cs_a, cd_a, W0a, as0a, ad0a, Wt, h_bf, ssrc, sdst,
             mbuf, zrbuf, ebuf, acc0, stream);
    run_conv(bf_in, rp_b, cs_b, cd_b, W0b, as0b, ad0b, Wt, h_bf, ssrc, sdst,
             mbuf, zrbuf, ebuf, acc0, stream);
    leaky_bf16_kernel<<<nf4_blocks, 256, 0, stream>>>(acc0, bf_in);

    // ---- layer 1 ----
    bias_init_kernel<<<nf_blocks, 256, 0, stream>>>(b1a, b1b, acc1);
    run_conv(bf_in, rp_a, cs_a, cd_a, W1a, as1a, ad1a, Wt, h_bf, ssrc, sdst,
             mbuf, zrbuf, ebuf, acc1, stream);
    run_conv(bf_in, rp_b, cs_b, cd_b, W1b, as1b, ad1b, Wt, h_bf, ssrc, sdst,
             mbuf, zrbuf, ebuf, acc1, stream);

    // ---- output projection ----
    convert_bf16_kernel<<<nf4_blocks, 256, 0, stream>>>(acc1, bf_in, (int)NF);
    wt_kernel<<<NC, 256, 0, stream>>>(Wout, Wt, NC);
    dim3 ogrid((N_NODES + 127) / 128, (NC + 127) / 128);
    mfma_gemm_bt<<<ogrid, 256, 0, stream>>>(bf_in, Wt, out, nullptr, bout,
                                            N_NODES, NC);
}

// Round 7
// 727.823 us; speedup vs baseline: 2.2915x; 1.0068x over previous
//
#include <hip/hip_runtime.h>
#include <math.h>

#define N_NODES 50000
#define E_EDGES 250000
#define HD 256          // H * D
#define NH 4
#define DH 64
#define NC 153
#define KDIM 256        // all GEMMs have K = 256

// ---------- fp32 <-> bf16 ----------
__device__ __forceinline__ unsigned short f2bf(float f) {
    unsigned u = __float_as_uint(f);
    u = u + 0x7FFFu + ((u >> 16) & 1u);
    return (unsigned short)(u >> 16);
}
__device__ __forceinline__ float bf2f(unsigned short b) {
    return __uint_as_float(((unsigned)b) << 16);
}

typedef __attribute__((ext_vector_type(8))) short bf16x8;
typedef __attribute__((ext_vector_type(4))) float f32x4;

// ================= K=256-specialized bf16 MFMA GEMM =================
// C[M,Nc] = A[M,256] @ BT[256rows,256]^T (+bias), Nc <= 256.
// Block: 64 rows x 256 cols, 4 waves (wave w owns cols w*64..w*64+63).
// A panel (64x256) staged to LDS ONCE -> barrier-free K-loop.
// B fragments loaded directly global->VGPR (BT is [N,K] row-major, frag is
// contiguous bf16x8; BT zero-padded to 256 rows so no bounds checks).
// LDS stride 296 ushort = 148 dwords === 20 mod 32 -> only free 2-way conflicts.
#define LDA 296

__global__ __launch_bounds__(256) void gemm_k256(
        const unsigned short* __restrict__ A, const unsigned short* __restrict__ BT,
        float* __restrict__ Cf, unsigned short* __restrict__ Cbf,
        const float* __restrict__ bias, int M, int Nc) {
    __shared__ unsigned short As[64 * LDA];
    const int tid = threadIdx.x;
    const int lane = tid & 63;
    const int wave = tid >> 6;
    const int row0 = blockIdx.x * 64;
    const int wn = wave * 64;
    const int quad = lane >> 4;
    const int l16 = lane & 15;

    // ---- stage A tile (64 x 256) into LDS, once ----
    #pragma unroll
    for (int j = 0; j < 8; j++) {
        const int chunk = tid + 256 * j;       // 2048 chunks of 8 ushort
        const int r = chunk >> 5;              // 32 chunks per row
        const int c = (chunk & 31) * 8;
        const int gr = row0 + r;
        bf16x8 v = (bf16x8)0;
        if (gr < M) v = *(const bf16x8*)&A[(size_t)gr * KDIM + c];
        *(bf16x8*)&As[r * LDA + c] = v;
    }
    __syncthreads();

    f32x4 acc[4][4];
    #pragma unroll
    for (int i = 0; i < 4; i++)
        #pragma unroll
        for (int j = 0; j < 4; j++) acc[i][j] = (f32x4)0.f;

    const int a_off = l16 * LDA + quad * 8;                       // + mt*16*LDA + k0
    const size_t b_off = (size_t)(wn + l16) * KDIM + quad * 8;    // + nt*16*KDIM + k0

    bf16x8 a_cur[4], b_cur[4], a_nxt[4], b_nxt[4];
    #pragma unroll
    for (int t = 0; t < 4; t++) {
        a_cur[t] = *(const bf16x8*)&As[t * 16 * LDA + a_off];
        b_cur[t] = *(const bf16x8*)&BT[b_off + (size_t)t * 16 * KDIM];
    }

    #pragma unroll
    for (int kk = 0; kk < 8; kk++) {
        const int k1 = (kk + 1) * 32;
        if (kk < 7) {
            #pragma unroll
            for (int t = 0; t < 4; t++) {
                a_nxt[t] = *(const bf16x8*)&As[t * 16 * LDA + a_off + k1];
                b_nxt[t] = *(const bf16x8*)&BT[b_off + (size_t)t * 16 * KDIM + k1];
            }
        }
        #pragma unroll
        for (int mt = 0; mt < 4; mt++)
            #pragma unroll
            for (int nt = 0; nt < 4; nt++)
                acc[mt][nt] = __builtin_amdgcn_mfma_f32_16x16x32_bf16(
                                  a_cur[mt], b_cur[nt], acc[mt][nt], 0, 0, 0);
        #pragma unroll
        for (int t = 0; t < 4; t++) { a_cur[t] = a_nxt[t]; b_cur[t] = b_nxt[t]; }
    }

    // epilogue: D col = lane&15, row = quad*4 + reg
    #pragma unroll
    for (int mt = 0; mt < 4; mt++) {
        #pragma unroll
        for (int nt = 0; nt < 4; nt++) {
            const int n = wn + nt * 16 + l16;
            if (n >= Nc) continue;
            const float bv = bias ? bias[n] : 0.f;
            #pragma unroll
            for (int r = 0; r < 4; r++) {
                const int m = row0 + mt * 16 + quad * 4 + r;
                if (m < M) {
                    const float v = acc[mt][nt][r] + bv;
                    if (Cf)  Cf[(size_t)m * Nc + n] = v;
                    if (Cbf) Cbf[(size_t)m * Nc + n] = f2bf(v);
                }
            }
        }
    }
}

// ---------- fp32 -> bf16 conversion (vectorized) ----------
__global__ __launch_bounds__(256) void convert_bf16_kernel(
        const float* __restrict__ in, unsigned short* __restrict__ out, int n) {
    const int i = (blockIdx.x * 256 + threadIdx.x) * 4;
    if (i + 3 < n) {
        const float4 v = *(const float4*)&in[i];
        ushort4 o;
        o.x = f2bf(v.x); o.y = f2bf(v.y); o.z = f2bf(v.z); o.w = f2bf(v.w);
        *(ushort4*)&out[i] = o;
    } else {
        for (int j = i; j < n; j++) out[j] = f2bf(in[j]);
    }
}

// ---------- fused leaky-relu (0.01) in-place + bf16 copy ----------
__global__ __launch_bounds__(256) void leaky_bf16_kernel(
        float* __restrict__ x, unsigned short* __restrict__ out) {
    const int i = (blockIdx.x * 256 + threadIdx.x) * 4;
    if (i >= N_NODES * HD) return;
    float4 v = *(float4*)&x[i];
    v.x = (v.x >= 0.f) ? v.x : 0.01f * v.x;
    v.y = (v.y >= 0.f) ? v.y : 0.01f * v.y;
    v.z = (v.z >= 0.f) ? v.z : 0.01f * v.z;
    v.w = (v.w >= 0.f) ? v.w : 0.01f * v.w;
    *(float4*)&x[i] = v;
    ushort4 o;
    o.x = f2bf(v.x); o.y = f2bf(v.y); o.z = f2bf(v.z); o.w = f2bf(v.w);
    *(ushort4*)&out[i] = o;
}

// ---------- weight transpose+convert: W[K,Nc] fp32 -> Wt[256,K] bf16, zero-pad ----------
__global__ __launch_bounds__(256) void wt_kernel(
        const float* __restrict__ W, unsigned short* __restrict__ Wt, int Nc) {
    const int idx = blockIdx.x * 256 + threadIdx.x;   // = n*KDIM + k, full 256x256
    const int n = idx >> 8, k = idx & 255;
    Wt[idx] = (n < Nc) ? f2bf(W[(size_t)k * Nc + n]) : (unsigned short)0;
}

// ---------- CSR construction ----------
__global__ __launch_bounds__(256) void zero_int_kernel(int* __restrict__ p, int n) {
    const int i = blockIdx.x * 256 + threadIdx.x;
    if (i < n) p[i] = 0;
}

__global__ __launch_bounds__(256) void hist_kernel(
        const int* __restrict__ ei, int* __restrict__ deg) {
    const int e = blockIdx.x * 256 + threadIdx.x;
    if (e < E_EDGES) atomicAdd(&deg[ei[E_EDGES + e]], 1);
}

__global__ __launch_bounds__(1024) void scan_local_kernel(
        const int* __restrict__ deg, int* __restrict__ excl,
        int* __restrict__ bsums, int n) {
    __shared__ int wsum[16];
    const int i = blockIdx.x * 1024 + threadIdx.x;
    const int lane = threadIdx.x & 63;
    const int wid = threadIdx.x >> 6;
    const int v = (i < n) ? deg[i] : 0;
    int s = v;
    #pragma unroll
    for (int off = 1; off < 64; off <<= 1) {
        const int t = __shfl_up(s, off);
        if (lane >= off) s += t;
    }
    if (lane == 63) wsum[wid] = s;
    __syncthreads();
    if (wid == 0) {
        int wv = (lane < 16) ? wsum[lane] : 0;
        #pragma unroll
        for (int off = 1; off < 16; off <<= 1) {
            const int t = __shfl_up(wv, off);
            if (lane >= off) wv += t;
        }
        if (lane < 16) wsum[lane] = wv;
    }
    __syncthreads();
    const int woff = (wid > 0) ? wsum[wid - 1] : 0;
    if (i < n) excl[i] = s - v + woff;
    if (threadIdx.x == 1023) bsums[blockIdx.x] = wsum[15];
}

__global__ __launch_bounds__(64) void scan_bsums_kernel(
        int* __restrict__ bsums, int* __restrict__ row_ptr, int nb, int n) {
    const int lane = threadIdx.x;
    const int v = (lane < nb) ? bsums[lane] : 0;
    int s = v;
    #pragma unroll
    for (int off = 1; off < 64; off <<= 1) {
        const int t = __shfl_up(s, off);
        if (lane >= off) s += t;
    }
    if (lane < nb) bsums[lane] = s - v;
    if (lane == 63) row_ptr[n] = s;
}

__global__ __launch_bounds__(256) void scan_add_kernel(
        const int* __restrict__ excl, const int* __restrict__ bsums,
        int* __restrict__ row_ptr, int* __restrict__ cursor, int n) {
    const int i = blockIdx.x * 256 + threadIdx.x;
    if (i >= n) return;
    const int v = excl[i] + bsums[i >> 10];
    row_ptr[i] = v;
    cursor[i]  = v;
}

__global__ __launch_bounds__(256) void scatter_kernel(
        const int* __restrict__ ei, int* __restrict__ cursor,
        int* __restrict__ col_src, int* __restrict__ col_dst) {
    const int e = blockIdx.x * 256 + threadIdx.x;
    if (e >= E_EDGES) return;
    const int src = ei[e], dst = ei[E_EDGES + e];
    const int pos = atomicAdd(&cursor[dst], 1);
    col_src[pos] = src;
    col_dst[pos] = dst;
}

// ---------- per-node attention scores (bf16 h, lane owns 4 contiguous elems) ----------
__global__ __launch_bounds__(256) void scores_kernel(
        const unsigned short* __restrict__ hbf, const float* __restrict__ asrc,
        const float* __restrict__ adst, float* __restrict__ ssrc,
        float* __restrict__ sdst) {
    const int node = blockIdx.x * 4 + (threadIdx.x >> 6);
    const int lane = threadIdx.x & 63;
    if (node >= N_NODES) return;
    const ushort4 hv = *(const ushort4*)&hbf[(size_t)node * HD + lane * 4];
    const float4 av = *(const float4*)&asrc[lane * 4];
    const float4 dv = *(const float4*)&adst[lane * 4];
    const float h0 = bf2f(hv.x), h1 = bf2f(hv.y), h2 = bf2f(hv.z), h3 = bf2f(hv.w);
    float rs = h0 * av.x + h1 * av.y + h2 * av.z + h3 * av.w;
    float rd = h0 * dv.x + h1 * dv.y + h2 * dv.z + h3 * dv.w;
    #pragma unroll
    for (int off = 1; off < 16; off <<= 1) {
        rs += __shfl_xor(rs, off);
        rd += __shfl_xor(rd, off);
    }
    if ((lane & 15) == 0) {
        const int hh = lane >> 4;
        ssrc[node * NH + hh] = rs;
        sdst[node * NH + hh] = rd;
    }
}

// ---------- S1: per (node,head) thread computes m and 1/(z+eps) over CSR ----------
__global__ __launch_bounds__(256) void seg_mz_kernel(
        const int* __restrict__ rp, const int* __restrict__ cs,
        const float* __restrict__ ssrc, const float* __restrict__ sdst,
        float* __restrict__ mbuf, float* __restrict__ zrbuf) {
    const int t = blockIdx.x * 256 + threadIdx.x;
    if (t >= N_NODES * NH) return;
    const int node = t >> 2, hh = t & 3;
    const int beg = rp[node], end = rp[node + 1];
    const float sd = sdst[t];
    float m = -INFINITY;
    for (int e = beg; e < end; e++) {
        float s = ssrc[cs[e] * NH + hh] + sd;
        s = (s >= 0.f) ? s : 0.2f * s;
        m = fmaxf(m, s);
    }
    float z = 0.f;
    for (int e = beg; e < end; e++) {
        float s = ssrc[cs[e] * NH + hh] + sd;
        s = (s >= 0.f) ? s : 0.2f * s;
        z += expf(s - m);
    }
    mbuf[t]  = m;
    zrbuf[t] = 1.f / (z + 1e-16f);
}

// ---------- S2: per (edge,head) thread computes alpha in CSR order ----------
__global__ __launch_bounds__(256) void alpha_kernel(
        const int* __restrict__ cs, const int* __restrict__ cd,
        const float* __restrict__ ssrc, const float* __restrict__ sdst,
        const float* __restrict__ mbuf, const float* __restrict__ zrbuf,
        float* __restrict__ ebuf) {
    const int t = blockIdx.x * 256 + threadIdx.x;
    if (t >= E_EDGES * NH) return;
    const int pos = t >> 2, hh = t & 3;
    const int src = cs[pos], dst = cd[pos];
    float s = ssrc[src * NH + hh] + sdst[dst * NH + hh];
    s = (s >= 0.f) ? s : 0.2f * s;
    ebuf[t] = expf(s - mbuf[dst * NH + hh]) * zrbuf[dst * NH + hh];
}

// ---------- S3: streaming aggregation over bf16 h, wave per node ----------
__global__ __launch_bounds__(256) void aggregate_csr_kernel(
        const int* __restrict__ rp, const int* __restrict__ cs,
        const unsigned short* __restrict__ hbf, const float* __restrict__ ebuf,
        float* __restrict__ acc) {
    const int node = blockIdx.x * 4 + (threadIdx.x >> 6);
    const int lane = threadIdx.x & 63;
    if (node >= N_NODES) return;
    const int beg = rp[node], end = rp[node + 1];
    const int hh = lane >> 4;

    float4 a = make_float4(0.f, 0.f, 0.f, 0.f);
    for (int e = beg; e < end; e++) {
        const int src = cs[e];
        const float al = ebuf[e * NH + hh];
        const ushort4 hv = *(const ushort4*)&hbf[(size_t)src * HD + lane * 4];
        a.x = fmaf(al, bf2f(hv.x), a.x);
        a.y = fmaf(al, bf2f(hv.y), a.y);
        a.z = fmaf(al, bf2f(hv.z), a.z);
        a.w = fmaf(al, bf2f(hv.w), a.w);
    }
    float4* op = (float4*)&acc[(size_t)node * HD + lane * 4];
    float4 o = *op;
    o.x += a.x; o.y += a.y; o.z += a.z; o.w += a.w;
    *op = o;
}

// ---------- acc init with summed biases ----------
__global__ __launch_bounds__(256) void bias_init_kernel(
        const float* __restrict__ b1, const float* __restrict__ b2,
        float* __restrict__ acc) {
    const int idx = blockIdx.x * 256 + threadIdx.x;
    if (idx >= N_NODES * HD) return;
    const int c = idx & (HD - 1);
    acc[idx] = b1[c] + b2[c];
}

// ---------- host-side helpers ----------
static void run_conv(const unsigned short* a_bf, const int* row_ptr,
                     const int* col_src, const int* col_dst,
                     const float* W, const float* asrc, const float* adst,
                     unsigned short* Wt, unsigned short* h_bf,
                     float* ssrc, float* sdst,
                     float* mbuf, float* zrbuf, float* ebuf, float* acc,
                     hipStream_t stream) {
    wt_kernel<<<KDIM, 256, 0, stream>>>(W, Wt, HD);
    gemm_k256<<<(N_NODES + 63) / 64, 256, 0, stream>>>(
        a_bf, Wt, nullptr, h_bf, nullptr, N_NODES, HD);
    scores_kernel<<<(N_NODES + 3) / 4, 256, 0, stream>>>(h_bf, asrc, adst, ssrc, sdst);
    seg_mz_kernel<<<(N_NODES * NH + 255) / 256, 256, 0, stream>>>(
        row_ptr, col_src, ssrc, sdst, mbuf, zrbuf);
    alpha_kernel<<<(E_EDGES * NH + 255) / 256, 256, 0, stream>>>(
        col_src, col_dst, ssrc, sdst, mbuf, zrbuf, ebuf);
    aggregate_csr_kernel<<<(N_NODES + 3) / 4, 256, 0, stream>>>(
        row_ptr, col_src, h_bf, ebuf, acc);
}

static void build_csr(const int* ei, int* deg, int* cursor, int* row_ptr,
                      int* col_src, int* col_dst, int* excl, int* bsums,
                      hipStream_t stream) {
    const int nb  = (N_NODES + 255) / 256;
    const int eb  = (E_EDGES + 255) / 256;
    const int sb  = (N_NODES + 1023) / 1024;
    zero_int_kernel<<<nb, 256, 0, stream>>>(deg, N_NODES);
    hist_kernel<<<eb, 256, 0, stream>>>(ei, deg);
    scan_local_kernel<<<sb, 1024, 0, stream>>>(deg, excl, bsums, N_NODES);
    scan_bsums_kernel<<<1, 64, 0, stream>>>(bsums, row_ptr, sb, N_NODES);
    scan_add_kernel<<<nb, 256, 0, stream>>>(excl, bsums, row_ptr, cursor, N_NODES);
    scatter_kernel<<<eb, 256, 0, stream>>>(ei, cursor, col_src, col_dst);
}

extern "C" void kernel_launch(void* const* d_in, const int* in_sizes, int n_in,
                              void* d_out, int out_size, void* d_ws, size_t ws_size,
                              hipStream_t stream) {
    const float* x    = (const float*)d_in[0];
    const int*   ei_a = (const int*)d_in[1];
    const int*   ei_b = (const int*)d_in[2];
    const float* W0a = (const float*)d_in[3];
    const float* as0a = (const float*)d_in[4];
    const float* ad0a = (const float*)d_in[5];
    const float* b0a = (const float*)d_in[6];
    const float* W0b = (const float*)d_in[7];
    const float* as0b = (const float*)d_in[8];
    const float* ad0b = (const float*)d_in[9];
    const float* b0b = (const float*)d_in[10];
    const float* W1a = (const float*)d_in[11];
    const float* as1a = (const float*)d_in[12];
    const float* ad1a = (const float*)d_in[13];
    const float* b1a = (const float*)d_in[14];
    const float* W1b = (const float*)d_in[15];
    const float* as1b = (const float*)d_in[16];
    const float* ad1b = (const float*)d_in[17];
    const float* b1b = (const float*)d_in[18];
    const float* Wout = (const float*)d_in[19];
    const float* bout = (const float*)d_in[20];
    float* out = (float*)d_out;

    // workspace carve
    float* ws = (float*)d_ws;
    const size_t NF = (size_t)N_NODES * HD;   // 12.8M
    float* acc0   = ws;                         // NF
    float* acc1   = acc0 + NF;                  // NF
    unsigned short* h_bf  = (unsigned short*)(acc1 + NF);       // NF ushort
    unsigned short* bf_in = h_bf + NF;                          // NF ushort
    unsigned short* Wt    = bf_in + NF;                         // 256*256 ushort
    float* ssrc   = (float*)(Wt + (size_t)KDIM * KDIM);         // N*4
    float* sdst   = ssrc + (size_t)N_NODES * NH;                // N*4
    float* mbuf   = sdst + (size_t)N_NODES * NH;                // N*4
    float* zrbuf  = mbuf + (size_t)N_NODES * NH;                // N*4
    float* ebuf   = zrbuf + (size_t)N_NODES * NH;               // E*4
    int*   ibase  = (int*)(ebuf + (size_t)E_EDGES * NH);
    int* deg     = ibase;
    int* cursor  = deg + N_NODES;
    int* rp_a    = cursor + N_NODES;
    int* cs_a    = rp_a + N_NODES + 1;
    int* cd_a    = cs_a + E_EDGES;
    int* rp_b    = cd_a + E_EDGES;
    int* cs_b    = rp_b + N_NODES + 1;
    int* cd_b    = cs_b + E_EDGES;
    int* excl    = cd_b + E_EDGES;
    int* bsums   = excl + N_NODES;

    const int nf_blocks  = (int)((NF + 255) / 256);
    const int nf4_blocks = (int)((NF / 4 + 255) / 256);

    // ---- CSR for both edge types (reused by both layers) ----
    build_csr(ei_a, deg, cursor, rp_a, cs_a, cd_a, excl, bsums, stream);
    build_csr(ei_b, deg, cursor, rp_b, cs_b, cd_b, excl, bsums, stream);

    // ---- layer 0 ----
    convert_bf16_kernel<<<nf4_blocks, 256, 0, stream>>>(x, bf_in, (int)NF);
    bias_init_kernel<<<nf_blocks, 256, 0, stream>>>(b0a, b0b, acc0);
    run_conv(bf_in, rp_a, cs_a, cd_a, W0a, as0a, ad0a, Wt, h_bf, ssrc, sdst,
             mbuf, zrbuf, ebuf, acc0, stream);
    run_conv(bf_in, rp_b, cs_b, cd_b, W0b, as0b, ad0b, Wt, h_bf, ssrc, sdst,
             mbuf, zrbuf, ebuf, acc0, stream);
    leaky_bf16_kernel<<<nf4_blocks, 256, 0, stream>>>(acc0, bf_in);

    // ---- layer 1 ----
    bias_init_kernel<<<nf_blocks, 256, 0, stream>>>(b1a, b1b, acc1);
    run_conv(bf_in, rp_a, cs_a, cd_a, W1a, as1a, ad1a, Wt, h_bf, ssrc, sdst,
             mbuf, zrbuf, ebuf, acc1, stream);
    run_conv(bf_in, rp_b, cs_b, cd_b, W1b, as1b, ad1b, Wt, h_bf, ssrc, sdst,
             mbuf, zrbuf, ebuf, acc1, stream);

    // ---- output projection ----
    convert_bf16_kernel<<<nf4_blocks, 256, 0, stream>>>(acc1, bf_in, (int)NF);
    wt_kernel<<<KDIM, 256, 0, stream>>>(Wout, Wt, NC);
    gemm_k256<<<(N_NODES + 63) / 64, 256, 0, stream>>>(
        bf_in, Wt, out, nullptr, bout, N_NODES, NC);
}

// Round 8
// 623.163 us; speedup vs baseline: 2.6764x; 1.1680x over previous
//
#include <hip/hip_runtime.h>
#include <math.h>

#define N_NODES 50000
#define E_EDGES 250000
#define HD 256          // H * D per edge type
#define NH 4
#define DH 64
#define NC 153
#define KDIM 256        // all GEMMs have K = 256
#define HD2 512         // both edge types concatenated

// ---------- fp32 <-> bf16 ----------
__device__ __forceinline__ unsigned short f2bf(float f) {
    unsigned u = __float_as_uint(f);
    u = u + 0x7FFFu + ((u >> 16) & 1u);
    return (unsigned short)(u >> 16);
}
__device__ __forceinline__ float bf2f(unsigned short b) {
    return __uint_as_float(((unsigned)b) << 16);
}

typedef __attribute__((ext_vector_type(8))) short bf16x8;
typedef __attribute__((ext_vector_type(4))) float f32x4;

// ================= K=256 bf16 MFMA GEMM, B-in-LDS, A streamed =================
// C[M,Ncols] = A[M,256] @ BT[Ncols,256]^T (+bias), BT zero-padded to 64*gridDim.y rows.
// Block: 256 rows x 64 cols. 4 waves stacked in M share one B tile (64x256, LDS).
// A-fragments stream global->VGPR (contiguous bf16x8/lane, 1KB/instr coalesced).
#define LDB 296   // ushort; 148 dwords === 20 mod 32 -> worst 2-way LDS conflict (free)

__global__ __launch_bounds__(256) void gemm_k256(
        const unsigned short* __restrict__ A, const unsigned short* __restrict__ BT,
        float* __restrict__ Cf, unsigned short* __restrict__ Cbf,
        const float* __restrict__ bias, int M, int Ncols) {
    __shared__ unsigned short Bs[64 * LDB];
    const int tid = threadIdx.x;
    const int lane = tid & 63;
    const int wave = tid >> 6;
    const int row0 = blockIdx.x * 256 + wave * 64;
    const int col0 = blockIdx.y * 64;
    const int quad = lane >> 4;
    const int l16 = lane & 15;

    // ---- stage B tile (64 cols x 256 K) into LDS once ----
    #pragma unroll
    for (int j = 0; j < 8; j++) {
        const int chunk = tid + 256 * j;       // 2048 chunks of 8 ushort
        const int r = chunk >> 5;              // 0..63 (output col)
        const int c = (chunk & 31) * 8;        // k offset
        *(bf16x8*)&Bs[r * LDB + c] =
            *(const bf16x8*)&BT[(size_t)(col0 + r) * KDIM + c];
    }
    __syncthreads();

    f32x4 acc[4][4];
    #pragma unroll
    for (int i = 0; i < 4; i++)
        #pragma unroll
        for (int j = 0; j < 4; j++) acc[i][j] = (f32x4)0.f;

    // per-mt A offsets (row clamped for tail block; stores are masked anyway)
    size_t a_off[4];
    #pragma unroll
    for (int mt = 0; mt < 4; mt++) {
        int gr = row0 + mt * 16 + l16;
        if (gr >= M) gr = M - 1;
        a_off[mt] = (size_t)gr * KDIM + quad * 8;
    }
    const int b_off = l16 * LDB + quad * 8;

    bf16x8 a_cur[4], b_cur[4], a_nxt[4], b_nxt[4];
    #pragma unroll
    for (int t = 0; t < 4; t++) {
        a_cur[t] = *(const bf16x8*)&A[a_off[t]];
        b_cur[t] = *(const bf16x8*)&Bs[t * 16 * LDB + b_off];
    }

    #pragma unroll
    for (int kk = 0; kk < 8; kk++) {
        const int k1 = (kk + 1) * 32;
        if (kk < 7) {
            #pragma unroll
            for (int t = 0; t < 4; t++) {
                a_nxt[t] = *(const bf16x8*)&A[a_off[t] + k1];
                b_nxt[t] = *(const bf16x8*)&Bs[t * 16 * LDB + b_off + k1];
            }
        }
        #pragma unroll
        for (int mt = 0; mt < 4; mt++)
            #pragma unroll
            for (int nt = 0; nt < 4; nt++)
                acc[mt][nt] = __builtin_amdgcn_mfma_f32_16x16x32_bf16(
                                  a_cur[mt], b_cur[nt], acc[mt][nt], 0, 0, 0);
        #pragma unroll
        for (int t = 0; t < 4; t++) { a_cur[t] = a_nxt[t]; b_cur[t] = b_nxt[t]; }
    }

    // epilogue: D col = lane&15, row = quad*4 + reg
    #pragma unroll
    for (int mt = 0; mt < 4; mt++) {
        #pragma unroll
        for (int nt = 0; nt < 4; nt++) {
            const int n = col0 + nt * 16 + l16;
            if (n >= Ncols) continue;
            const float bv = bias ? bias[n] : 0.f;
            #pragma unroll
            for (int r = 0; r < 4; r++) {
                const int m = row0 + mt * 16 + quad * 4 + r;
                if (m < M) {
                    const float v = acc[mt][nt][r] + bv;
                    if (Cf)  Cf[(size_t)m * Ncols + n] = v;
                    if (Cbf) Cbf[(size_t)m * Ncols + n] = f2bf(v);
                }
            }
        }
    }
}

// ---------- fp32 -> bf16 conversion (vectorized) ----------
__global__ __launch_bounds__(256) void convert_bf16_kernel(
        const float* __restrict__ in, unsigned short* __restrict__ out, int n) {
    const int i = (blockIdx.x * 256 + threadIdx.x) * 4;
    if (i + 3 < n) {
        const float4 v = *(const float4*)&in[i];
        ushort4 o;
        o.x = f2bf(v.x); o.y = f2bf(v.y); o.z = f2bf(v.z); o.w = f2bf(v.w);
        *(ushort4*)&out[i] = o;
    } else {
        for (int j = i; j < n; j++) out[j] = f2bf(in[j]);
    }
}

// ---------- fused leaky-relu (0.01) in-place + bf16 copy ----------
__global__ __launch_bounds__(256) void leaky_bf16_kernel(
        float* __restrict__ x, unsigned short* __restrict__ out) {
    const int i = (blockIdx.x * 256 + threadIdx.x) * 4;
    if (i >= N_NODES * HD) return;
    float4 v = *(float4*)&x[i];
    v.x = (v.x >= 0.f) ? v.x : 0.01f * v.x;
    v.y = (v.y >= 0.f) ? v.y : 0.01f * v.y;
    v.z = (v.z >= 0.f) ? v.z : 0.01f * v.z;
    v.w = (v.w >= 0.f) ? v.w : 0.01f * v.w;
    *(float4*)&x[i] = v;
    ushort4 o;
    o.x = f2bf(v.x); o.y = f2bf(v.y); o.z = f2bf(v.z); o.w = f2bf(v.w);
    *(ushort4*)&out[i] = o;
}

// ---------- dual weight transpose+convert: Wa,Wb[K,256] -> Wt[512,K] bf16 ----------
__global__ __launch_bounds__(256) void wt2_kernel(
        const float* __restrict__ Wa, const float* __restrict__ Wb,
        unsigned short* __restrict__ Wt) {
    const int idx = blockIdx.x * 256 + threadIdx.x;   // n*KDIM + k over 512x256
    const int n = idx >> 8, k = idx & 255;
    Wt[idx] = (n < HD) ? f2bf(Wa[(size_t)k * HD + n])
                       : f2bf(Wb[(size_t)k * HD + (n - HD)]);
}

// ---------- single weight transpose+convert with zero-pad to 256 rows ----------
__global__ __launch_bounds__(256) void wt_kernel(
        const float* __restrict__ W, unsigned short* __restrict__ Wt, int Nc) {
    const int idx = blockIdx.x * 256 + threadIdx.x;
    const int n = idx >> 8, k = idx & 255;
    Wt[idx] = (n < Nc) ? f2bf(W[(size_t)k * Nc + n]) : (unsigned short)0;
}

// ---------- CSR construction ----------
__global__ __launch_bounds__(256) void zero_int_kernel(int* __restrict__ p, int n) {
    const int i = blockIdx.x * 256 + threadIdx.x;
    if (i < n) p[i] = 0;
}

__global__ __launch_bounds__(256) void hist_kernel(
        const int* __restrict__ ei, int* __restrict__ deg) {
    const int e = blockIdx.x * 256 + threadIdx.x;
    if (e < E_EDGES) atomicAdd(&deg[ei[E_EDGES + e]], 1);
}

__global__ __launch_bounds__(1024) void scan_local_kernel(
        const int* __restrict__ deg, int* __restrict__ excl,
        int* __restrict__ bsums, int n) {
    __shared__ int wsum[16];
    const int i = blockIdx.x * 1024 + threadIdx.x;
    const int lane = threadIdx.x & 63;
    const int wid = threadIdx.x >> 6;
    const int v = (i < n) ? deg[i] : 0;
    int s = v;
    #pragma unroll
    for (int off = 1; off < 64; off <<= 1) {
        const int t = __shfl_up(s, off);
        if (lane >= off) s += t;
    }
    if (lane == 63) wsum[wid] = s;
    __syncthreads();
    if (wid == 0) {
        int wv = (lane < 16) ? wsum[lane] : 0;
        #pragma unroll
        for (int off = 1; off < 16; off <<= 1) {
            const int t = __shfl_up(wv, off);
            if (lane >= off) wv += t;
        }
        if (lane < 16) wsum[lane] = wv;
    }
    __syncthreads();
    const int woff = (wid > 0) ? wsum[wid - 1] : 0;
    if (i < n) excl[i] = s - v + woff;
    if (threadIdx.x == 1023) bsums[blockIdx.x] = wsum[15];
}

__global__ __launch_bounds__(64) void scan_bsums_kernel(
        int* __restrict__ bsums, int* __restrict__ row_ptr, int nb, int n) {
    const int lane = threadIdx.x;
    const int v = (lane < nb) ? bsums[lane] : 0;
    int s = v;
    #pragma unroll
    for (int off = 1; off < 64; off <<= 1) {
        const int t = __shfl_up(s, off);
        if (lane >= off) s += t;
    }
    if (lane < nb) bsums[lane] = s - v;
    if (lane == 63) row_ptr[n] = s;
}

__global__ __launch_bounds__(256) void scan_add_kernel(
        const int* __restrict__ excl, const int* __restrict__ bsums,
        int* __restrict__ row_ptr, int* __restrict__ cursor, int n) {
    const int i = blockIdx.x * 256 + threadIdx.x;
    if (i >= n) return;
    const int v = excl[i] + bsums[i >> 10];
    row_ptr[i] = v;
    cursor[i]  = v;
}

__global__ __launch_bounds__(256) void scatter_kernel(
        const int* __restrict__ ei, int* __restrict__ cursor,
        int* __restrict__ col_src, int* __restrict__ col_dst) {
    const int e = blockIdx.x * 256 + threadIdx.x;
    if (e >= E_EDGES) return;
    const int src = ei[e], dst = ei[E_EDGES + e];
    const int pos = atomicAdd(&cursor[dst], 1);
    col_src[pos] = src;
    col_dst[pos] = dst;
}

// ---------- per-node attention scores for BOTH etypes ----------
// h_ab[node][512]: cols 0..255 etype a, 256..511 etype b.
// Output layout: ss[node*8 + et*4 + hh].
__global__ __launch_bounds__(256) void scores2_kernel(
        const unsigned short* __restrict__ h_ab,
        const float* __restrict__ as_a, const float* __restrict__ ad_a,
        const float* __restrict__ as_b, const float* __restrict__ ad_b,
        float* __restrict__ ssrc8, float* __restrict__ sdst8) {
    const int node = blockIdx.x * 4 + (threadIdx.x >> 6);
    const int lane = threadIdx.x & 63;
    if (node >= N_NODES) return;
    const size_t base = (size_t)node * HD2 + lane * 4;

    const ushort4 ha = *(const ushort4*)&h_ab[base];
    const ushort4 hb = *(const ushort4*)&h_ab[base + HD];
    const float4 asa = *(const float4*)&as_a[lane * 4];
    const float4 ada = *(const float4*)&ad_a[lane * 4];
    const float4 asb = *(const float4*)&as_b[lane * 4];
    const float4 adb = *(const float4*)&ad_b[lane * 4];
    const float a0 = bf2f(ha.x), a1 = bf2f(ha.y), a2 = bf2f(ha.z), a3 = bf2f(ha.w);
    const float b0 = bf2f(hb.x), b1 = bf2f(hb.y), b2 = bf2f(hb.z), b3 = bf2f(hb.w);

    float rsa = a0 * asa.x + a1 * asa.y + a2 * asa.z + a3 * asa.w;
    float rda = a0 * ada.x + a1 * ada.y + a2 * ada.z + a3 * ada.w;
    float rsb = b0 * asb.x + b1 * asb.y + b2 * asb.z + b3 * asb.w;
    float rdb = b0 * adb.x + b1 * adb.y + b2 * adb.z + b3 * adb.w;
    #pragma unroll
    for (int off = 1; off < 16; off <<= 1) {
        rsa += __shfl_xor(rsa, off);
        rda += __shfl_xor(rda, off);
        rsb += __shfl_xor(rsb, off);
        rdb += __shfl_xor(rdb, off);
    }
    if ((lane & 15) == 0) {
        const int hh = lane >> 4;
        ssrc8[node * 8 + 0 + hh] = rsa;
        sdst8[node * 8 + 0 + hh] = rda;
        ssrc8[node * 8 + 4 + hh] = rsb;
        sdst8[node * 8 + 4 + hh] = rdb;
    }
}

// ---------- S1: per (node,etype,head) thread computes m and 1/(z+eps) ----------
__global__ __launch_bounds__(256) void seg_mz8_kernel(
        const int* __restrict__ rp_a, const int* __restrict__ cs_a,
        const int* __restrict__ rp_b, const int* __restrict__ cs_b,
        const float* __restrict__ ssrc8, const float* __restrict__ sdst8,
        float* __restrict__ m8, float* __restrict__ zr8) {
    const int t = blockIdx.x * 256 + threadIdx.x;
    if (t >= N_NODES * 8) return;
    const int node = t >> 3;
    const int r8 = t & 7;               // et*4 + hh
    const int et = r8 >> 2;
    const int* rp = et ? rp_b : rp_a;
    const int* cs = et ? cs_b : cs_a;
    const int beg = rp[node], end = rp[node + 1];
    const float sd = sdst8[t];
    float m = -INFINITY;
    for (int e = beg; e < end; e++) {
        float s = ssrc8[cs[e] * 8 + r8] + sd;
        s = (s >= 0.f) ? s : 0.2f * s;
        m = fmaxf(m, s);
    }
    float z = 0.f;
    for (int e = beg; e < end; e++) {
        float s = ssrc8[cs[e] * 8 + r8] + sd;
        s = (s >= 0.f) ? s : 0.2f * s;
        z += expf(s - m);
    }
    m8[t]  = m;
    zr8[t] = 1.f / (z + 1e-16f);
}

// ---------- S2: per (edge,head) alpha in CSR order, one etype ----------
__global__ __launch_bounds__(256) void alpha_kernel(
        const int* __restrict__ cs, const int* __restrict__ cd,
        const float* __restrict__ ssrc8, const float* __restrict__ sdst8,
        const float* __restrict__ m8, const float* __restrict__ zr8,
        float* __restrict__ ebuf, int et) {
    const int t = blockIdx.x * 256 + threadIdx.x;
    if (t >= E_EDGES * NH) return;
    const int pos = t >> 2, hh = t & 3;
    const int r8 = et * 4 + hh;
    const int src = cs[pos], dst = cd[pos];
    float s = ssrc8[src * 8 + r8] + sdst8[dst * 8 + r8];
    s = (s >= 0.f) ? s : 0.2f * s;
    ebuf[t] = expf(s - m8[dst * 8 + r8]) * zr8[dst * 8 + r8];
}

// ---------- S3: streaming aggregation over both etypes, wave per node ----------
__global__ __launch_bounds__(256) void aggregate_both_kernel(
        const int* __restrict__ rp_a, const int* __restrict__ cs_a,
        const int* __restrict__ rp_b, const int* __restrict__ cs_b,
        const unsigned short* __restrict__ h_ab,
        const float* __restrict__ ebuf_a, const float* __restrict__ ebuf_b,
        float* __restrict__ acc) {
    const int node = blockIdx.x * 4 + (threadIdx.x >> 6);
    const int lane = threadIdx.x & 63;
    if (node >= N_NODES) return;
    const int hh = lane >> 4;

    float4 a = make_float4(0.f, 0.f, 0.f, 0.f);
    {
        const int beg = rp_a[node], end = rp_a[node + 1];
        for (int e = beg; e < end; e++) {
            const int src = cs_a[e];
            const float al = ebuf_a[e * NH + hh];
            const ushort4 hv = *(const ushort4*)&h_ab[(size_t)src * HD2 + lane * 4];
            a.x = fmaf(al, bf2f(hv.x), a.x);
            a.y = fmaf(al, bf2f(hv.y), a.y);
            a.z = fmaf(al, bf2f(hv.z), a.z);
            a.w = fmaf(al, bf2f(hv.w), a.w);
        }
    }
    {
        const int beg = rp_b[node], end = rp_b[node + 1];
        for (int e = beg; e < end; e++) {
            const int src = cs_b[e];
            const float al = ebuf_b[e * NH + hh];
            const ushort4 hv = *(const ushort4*)&h_ab[(size_t)src * HD2 + HD + lane * 4];
            a.x = fmaf(al, bf2f(hv.x), a.x);
            a.y = fmaf(al, bf2f(hv.y), a.y);
            a.z = fmaf(al, bf2f(hv.z), a.z);
            a.w = fmaf(al, bf2f(hv.w), a.w);
        }
    }
    float4* op = (float4*)&acc[(size_t)node * HD + lane * 4];
    float4 o = *op;
    o.x += a.x; o.y += a.y; o.z += a.z; o.w += a.w;
    *op = o;
}

// ---------- acc init with summed biases ----------
__global__ __launch_bounds__(256) void bias_init_kernel(
        const float* __restrict__ b1, const float* __restrict__ b2,
        float* __restrict__ acc) {
    const int idx = blockIdx.x * 256 + threadIdx.x;
    if (idx >= N_NODES * HD) return;
    const int c = idx & (HD - 1);
    acc[idx] = b1[c] + b2[c];
}

// ---------- host-side helpers ----------
static void run_layer(const unsigned short* a_bf,
                      const int* rp_a, const int* cs_a, const int* cd_a,
                      const int* rp_b, const int* cs_b, const int* cd_b,
                      const float* Wa, const float* Wb,
                      const float* as_a, const float* ad_a,
                      const float* as_b, const float* ad_b,
                      unsigned short* Wt2, unsigned short* h_ab,
                      float* ssrc8, float* sdst8, float* m8, float* zr8,
                      float* ebuf_a, float* ebuf_b, float* acc,
                      hipStream_t stream) {
    wt2_kernel<<<HD2, 256, 0, stream>>>(Wa, Wb, Wt2);
    dim3 ggrid((N_NODES + 255) / 256, HD2 / 64);
    gemm_k256<<<ggrid, 256, 0, stream>>>(a_bf, Wt2, nullptr, h_ab, nullptr,
                                         N_NODES, HD2);
    scores2_kernel<<<(N_NODES + 3) / 4, 256, 0, stream>>>(
        h_ab, as_a, ad_a, as_b, ad_b, ssrc8, sdst8);
    seg_mz8_kernel<<<(N_NODES * 8 + 255) / 256, 256, 0, stream>>>(
        rp_a, cs_a, rp_b, cs_b, ssrc8, sdst8, m8, zr8);
    const int ab = (E_EDGES * NH + 255) / 256;
    alpha_kernel<<<ab, 256, 0, stream>>>(cs_a, cd_a, ssrc8, sdst8, m8, zr8, ebuf_a, 0);
    alpha_kernel<<<ab, 256, 0, stream>>>(cs_b, cd_b, ssrc8, sdst8, m8, zr8, ebuf_b, 1);
    aggregate_both_kernel<<<(N_NODES + 3) / 4, 256, 0, stream>>>(
        rp_a, cs_a, rp_b, cs_b, h_ab, ebuf_a, ebuf_b, acc);
}

static void build_csr(const int* ei, int* deg, int* cursor, int* row_ptr,
                      int* col_src, int* col_dst, int* excl, int* bsums,
                      hipStream_t stream) {
    const int nb  = (N_NODES + 255) / 256;
    const int eb  = (E_EDGES + 255) / 256;
    const int sb  = (N_NODES + 1023) / 1024;
    zero_int_kernel<<<nb, 256, 0, stream>>>(deg, N_NODES);
    hist_kernel<<<eb, 256, 0, stream>>>(ei, deg);
    scan_local_kernel<<<sb, 1024, 0, stream>>>(deg, excl, bsums, N_NODES);
    scan_bsums_kernel<<<1, 64, 0, stream>>>(bsums, row_ptr, sb, N_NODES);
    scan_add_kernel<<<nb, 256, 0, stream>>>(excl, bsums, row_ptr, cursor, N_NODES);
    scatter_kernel<<<eb, 256, 0, stream>>>(ei, cursor, col_src, col_dst);
}

extern "C" void kernel_launch(void* const* d_in, const int* in_sizes, int n_in,
                              void* d_out, int out_size, void* d_ws, size_t ws_size,
                              hipStream_t stream) {
    const float* x    = (const float*)d_in[0];
    const int*   ei_a = (const int*)d_in[1];
    const int*   ei_b = (const int*)d_in[2];
    const float* W0a = (const float*)d_in[3];
    const float* as0a = (const float*)d_in[4];
    const float* ad0a = (const float*)d_in[5];
    const float* b0a = (const float*)d_in[6];
    const float* W0b = (const float*)d_in[7];
    const float* as0b = (const float*)d_in[8];
    const float* ad0b = (const float*)d_in[9];
    const float* b0b = (const float*)d_in[10];
    const float* W1a = (const float*)d_in[11];
    const float* as1a = (const float*)d_in[12];
    const float* ad1a = (const float*)d_in[13];
    const float* b1a = (const float*)d_in[14];
    const float* W1b = (const float*)d_in[15];
    const float* as1b = (const float*)d_in[16];
    const float* ad1b = (const float*)d_in[17];
    const float* b1b = (const float*)d_in[18];
    const float* Wout = (const float*)d_in[19];
    const float* bout = (const float*)d_in[20];
    float* out = (float*)d_out;

    // workspace carve
    float* ws = (float*)d_ws;
    const size_t NF = (size_t)N_NODES * HD;     // 12.8M
    float* acc0   = ws;                          // NF
    float* acc1   = acc0 + NF;                   // NF
    unsigned short* h_ab  = (unsigned short*)(acc1 + NF);   // N*512 ushort
    unsigned short* bf_in = h_ab + (size_t)N_NODES * HD2;   // NF ushort
    unsigned short* Wt2   = bf_in + NF;                     // 512*256 ushort
    float* ssrc8  = (float*)(Wt2 + (size_t)HD2 * KDIM);     // N*8
    float* sdst8  = ssrc8 + (size_t)N_NODES * 8;            // N*8
    float* m8     = sdst8 + (size_t)N_NODES * 8;            // N*8
    float* zr8    = m8 + (size_t)N_NODES * 8;               // N*8
    float* ebuf_a = zr8 + (size_t)N_NODES * 8;              // E*4
    float* ebuf_b = ebuf_a + (size_t)E_EDGES * NH;          // E*4
    int*   ibase  = (int*)(ebuf_b + (size_t)E_EDGES * NH);
    int* deg     = ibase;
    int* cursor  = deg + N_NODES;
    int* rp_a    = cursor + N_NODES;
    int* cs_a    = rp_a + N_NODES + 1;
    int* cd_a    = cs_a + E_EDGES;
    int* rp_b    = cd_a + E_EDGES;
    int* cs_b    = rp_b + N_NODES + 1;
    int* cd_b    = cs_b + E_EDGES;
    int* excl    = cd_b + E_EDGES;
    int* bsums   = excl + N_NODES;

    const int nf_blocks  = (int)((NF + 255) / 256);
    const int nf4_blocks = (int)((NF / 4 + 255) / 256);

    // ---- CSR for both edge types (reused by both layers) ----
    build_csr(ei_a, deg, cursor, rp_a, cs_a, cd_a, excl, bsums, stream);
    build_csr(ei_b, deg, cursor, rp_b, cs_b, cd_b, excl, bsums, stream);

    // ---- layer 0 ----
    convert_bf16_kernel<<<nf4_blocks, 256, 0, stream>>>(x, bf_in, (int)NF);
    bias_init_kernel<<<nf_blocks, 256, 0, stream>>>(b0a, b0b, acc0);
    run_layer(bf_in, rp_a, cs_a, cd_a, rp_b, cs_b, cd_b, W0a, W0b,
              as0a, ad0a, as0b, ad0b, Wt2, h_ab, ssrc8, sdst8, m8, zr8,
              ebuf_a, ebuf_b, acc0, stream);
    leaky_bf16_kernel<<<nf4_blocks, 256, 0, stream>>>(acc0, bf_in);

    // ---- layer 1 ----
    bias_init_kernel<<<nf_blocks, 256, 0, stream>>>(b1a, b1b, acc1);
    run_layer(bf_in, rp_a, cs_a, cd_a, rp_b, cs_b, cd_b, W1a, W1b,
              as1a, ad1a, as1b, ad1b, Wt2, h_ab, ssrc8, sdst8, m8, zr8,
              ebuf_a, ebuf_b, acc1, stream);

    // ---- output projection ----
    convert_bf16_kernel<<<nf4_blocks, 256, 0, stream>>>(acc1, bf_in, (int)NF);
    wt_kernel<<<KDIM, 256, 0, stream>>>(Wout, Wt2, NC);
    dim3 ogrid((N_NODES + 255) / 256, 3);   // 3 x 64 cols covers NC=153
    gemm_k256<<<ogrid, 256, 0, stream>>>(bf_in, Wt2, out, nullptr, bout,
                                         N_NODES, NC);
}

// Round 9
// 515.655 us; speedup vs baseline: 3.2344x; 1.2085x over previous
//
#include <hip/hip_runtime.h>
#include <math.h>

#define N_NODES 50000
#define E_EDGES 250000
#define HD 256          // H * D per edge type
#define NH 4
#define DH 64
#define NC 153
#define KDIM 256        // all GEMMs have K = 256
#define HD2 512         // both edge types concatenated

// ---------- fp32 <-> bf16 ----------
__device__ __forceinline__ unsigned short f2bf(float f) {
    unsigned u = __float_as_uint(f);
    u = u + 0x7FFFu + ((u >> 16) & 1u);
    return (unsigned short)(u >> 16);
}
__device__ __forceinline__ float bf2f(unsigned short b) {
    return __uint_as_float(((unsigned)b) << 16);
}

typedef __attribute__((ext_vector_type(8))) short bf16x8;
typedef __attribute__((ext_vector_type(4))) float f32x4;

// ================= K=256 bf16 MFMA GEMM, B-in-LDS, A streamed =================
// C[M,Ncols] = A[M,256] @ BT[Ncols,256]^T (+bias), BT zero-padded to 64*gridDim.y rows.
// Block: 256 rows x 64 cols. 4 waves stacked in M share one B tile (64x256, LDS).
#define LDB 296   // ushort; 148 dwords === 20 mod 32 -> worst 2-way LDS conflict (free)

__global__ __launch_bounds__(256) void gemm_k256(
        const unsigned short* __restrict__ A, const unsigned short* __restrict__ BT,
        float* __restrict__ Cf, unsigned short* __restrict__ Cbf,
        const float* __restrict__ bias, int M, int Ncols) {
    __shared__ unsigned short Bs[64 * LDB];
    const int tid = threadIdx.x;
    const int lane = tid & 63;
    const int wave = tid >> 6;
    const int row0 = blockIdx.x * 256 + wave * 64;
    const int col0 = blockIdx.y * 64;
    const int quad = lane >> 4;
    const int l16 = lane & 15;

    #pragma unroll
    for (int j = 0; j < 8; j++) {
        const int chunk = tid + 256 * j;
        const int r = chunk >> 5;
        const int c = (chunk & 31) * 8;
        *(bf16x8*)&Bs[r * LDB + c] =
            *(const bf16x8*)&BT[(size_t)(col0 + r) * KDIM + c];
    }
    __syncthreads();

    f32x4 acc[4][4];
    #pragma unroll
    for (int i = 0; i < 4; i++)
        #pragma unroll
        for (int j = 0; j < 4; j++) acc[i][j] = (f32x4)0.f;

    size_t a_off[4];
    #pragma unroll
    for (int mt = 0; mt < 4; mt++) {
        int gr = row0 + mt * 16 + l16;
        if (gr >= M) gr = M - 1;
        a_off[mt] = (size_t)gr * KDIM + quad * 8;
    }
    const int b_off = l16 * LDB + quad * 8;

    bf16x8 a_cur[4], b_cur[4], a_nxt[4], b_nxt[4];
    #pragma unroll
    for (int t = 0; t < 4; t++) {
        a_cur[t] = *(const bf16x8*)&A[a_off[t]];
        b_cur[t] = *(const bf16x8*)&Bs[t * 16 * LDB + b_off];
    }

    #pragma unroll
    for (int kk = 0; kk < 8; kk++) {
        const int k1 = (kk + 1) * 32;
        if (kk < 7) {
            #pragma unroll
            for (int t = 0; t < 4; t++) {
                a_nxt[t] = *(const bf16x8*)&A[a_off[t] + k1];
                b_nxt[t] = *(const bf16x8*)&Bs[t * 16 * LDB + b_off + k1];
            }
        }
        #pragma unroll
        for (int mt = 0; mt < 4; mt++)
            #pragma unroll
            for (int nt = 0; nt < 4; nt++)
                acc[mt][nt] = __builtin_amdgcn_mfma_f32_16x16x32_bf16(
                                  a_cur[mt], b_cur[nt], acc[mt][nt], 0, 0, 0);
        #pragma unroll
        for (int t = 0; t < 4; t++) { a_cur[t] = a_nxt[t]; b_cur[t] = b_nxt[t]; }
    }

    #pragma unroll
    for (int mt = 0; mt < 4; mt++) {
        #pragma unroll
        for (int nt = 0; nt < 4; nt++) {
            const int n = col0 + nt * 16 + l16;
            if (n >= Ncols) continue;
            const float bv = bias ? bias[n] : 0.f;
            #pragma unroll
            for (int r = 0; r < 4; r++) {
                const int m = row0 + mt * 16 + quad * 4 + r;
                if (m < M) {
                    const float v = acc[mt][nt][r] + bv;
                    if (Cf)  Cf[(size_t)m * Ncols + n] = v;
                    if (Cbf) Cbf[(size_t)m * Ncols + n] = f2bf(v);
                }
            }
        }
    }
}

// ---------- fp32 -> bf16 conversion (vectorized) ----------
__global__ __launch_bounds__(256) void convert_bf16_kernel(
        const float* __restrict__ in, unsigned short* __restrict__ out, int n) {
    const int i = (blockIdx.x * 256 + threadIdx.x) * 4;
    if (i + 3 < n) {
        const float4 v = *(const float4*)&in[i];
        ushort4 o;
        o.x = f2bf(v.x); o.y = f2bf(v.y); o.z = f2bf(v.z); o.w = f2bf(v.w);
        *(ushort4*)&out[i] = o;
    } else {
        for (int j = i; j < n; j++) out[j] = f2bf(in[j]);
    }
}

// ---------- dual weight transpose+convert: Wa,Wb[K,256] -> Wt[512,K] bf16 ----------
__global__ __launch_bounds__(256) void wt2_kernel(
        const float* __restrict__ Wa, const float* __restrict__ Wb,
        unsigned short* __restrict__ Wt) {
    const int idx = blockIdx.x * 256 + threadIdx.x;
    const int n = idx >> 8, k = idx & 255;
    Wt[idx] = (n < HD) ? f2bf(Wa[(size_t)k * HD + n])
                       : f2bf(Wb[(size_t)k * HD + (n - HD)]);
}

// ---------- single weight transpose+convert with zero-pad to 256 rows ----------
__global__ __launch_bounds__(256) void wt_kernel(
        const float* __restrict__ W, unsigned short* __restrict__ Wt, int Nc) {
    const int idx = blockIdx.x * 256 + threadIdx.x;
    const int n = idx >> 8, k = idx & 255;
    Wt[idx] = (n < Nc) ? f2bf(W[(size_t)k * Nc + n]) : (unsigned short)0;
}

// ---------- CSR construction ----------
__global__ __launch_bounds__(256) void zero_int_kernel(int* __restrict__ p, int n) {
    const int i = blockIdx.x * 256 + threadIdx.x;
    if (i < n) p[i] = 0;
}

__global__ __launch_bounds__(256) void hist_kernel(
        const int* __restrict__ ei, int* __restrict__ deg) {
    const int e = blockIdx.x * 256 + threadIdx.x;
    if (e < E_EDGES) atomicAdd(&deg[ei[E_EDGES + e]], 1);
}

__global__ __launch_bounds__(1024) void scan_local_kernel(
        const int* __restrict__ deg, int* __restrict__ excl,
        int* __restrict__ bsums, int n) {
    __shared__ int wsum[16];
    const int i = blockIdx.x * 1024 + threadIdx.x;
    const int lane = threadIdx.x & 63;
    const int wid = threadIdx.x >> 6;
    const int v = (i < n) ? deg[i] : 0;
    int s = v;
    #pragma unroll
    for (int off = 1; off < 64; off <<= 1) {
        const int t = __shfl_up(s, off);
        if (lane >= off) s += t;
    }
    if (lane == 63) wsum[wid] = s;
    __syncthreads();
    if (wid == 0) {
        int wv = (lane < 16) ? wsum[lane] : 0;
        #pragma unroll
        for (int off = 1; off < 16; off <<= 1) {
            const int t = __shfl_up(wv, off);
            if (lane >= off) wv += t;
        }
        if (lane < 16) wsum[lane] = wv;
    }
    __syncthreads();
    const int woff = (wid > 0) ? wsum[wid - 1] : 0;
    if (i < n) excl[i] = s - v + woff;
    if (threadIdx.x == 1023) bsums[blockIdx.x] = wsum[15];
}

__global__ __launch_bounds__(64) void scan_bsums_kernel(
        int* __restrict__ bsums, int* __restrict__ row_ptr, int nb, int n) {
    const int lane = threadIdx.x;
    const int v = (lane < nb) ? bsums[lane] : 0;
    int s = v;
    #pragma unroll
    for (int off = 1; off < 64; off <<= 1) {
        const int t = __shfl_up(s, off);
        if (lane >= off) s += t;
    }
    if (lane < nb) bsums[lane] = s - v;
    if (lane == 63) row_ptr[n] = s;
}

__global__ __launch_bounds__(256) void scan_add_kernel(
        const int* __restrict__ excl, const int* __restrict__ bsums,
        int* __restrict__ row_ptr, int* __restrict__ cursor, int n) {
    const int i = blockIdx.x * 256 + threadIdx.x;
    if (i >= n) return;
    const int v = excl[i] + bsums[i >> 10];
    row_ptr[i] = v;
    cursor[i]  = v;
}

__global__ __launch_bounds__(256) void scatter_kernel(
        const int* __restrict__ ei, int* __restrict__ cursor,
        int* __restrict__ col_src, int* __restrict__ col_dst) {
    const int e = blockIdx.x * 256 + threadIdx.x;
    if (e >= E_EDGES) return;
    const int src = ei[e], dst = ei[E_EDGES + e];
    const int pos = atomicAdd(&cursor[dst], 1);
    col_src[pos] = src;
    col_dst[pos] = dst;
}

// ---------- per-node attention scores for BOTH etypes ----------
__global__ __launch_bounds__(256) void scores2_kernel(
        const unsigned short* __restrict__ h_ab,
        const float* __restrict__ as_a, const float* __restrict__ ad_a,
        const float* __restrict__ as_b, const float* __restrict__ ad_b,
        float* __restrict__ ssrc8, float* __restrict__ sdst8) {
    const int node = blockIdx.x * 4 + (threadIdx.x >> 6);
    const int lane = threadIdx.x & 63;
    if (node >= N_NODES) return;
    const size_t base = (size_t)node * HD2 + lane * 4;

    const ushort4 ha = *(const ushort4*)&h_ab[base];
    const ushort4 hb = *(const ushort4*)&h_ab[base + HD];
    const float4 asa = *(const float4*)&as_a[lane * 4];
    const float4 ada = *(const float4*)&ad_a[lane * 4];
    const float4 asb = *(const float4*)&as_b[lane * 4];
    const float4 adb = *(const float4*)&ad_b[lane * 4];
    const float a0 = bf2f(ha.x), a1 = bf2f(ha.y), a2 = bf2f(ha.z), a3 = bf2f(ha.w);
    const float b0 = bf2f(hb.x), b1 = bf2f(hb.y), b2 = bf2f(hb.z), b3 = bf2f(hb.w);

    float rsa = a0 * asa.x + a1 * asa.y + a2 * asa.z + a3 * asa.w;
    float rda = a0 * ada.x + a1 * ada.y + a2 * ada.z + a3 * ada.w;
    float rsb = b0 * asb.x + b1 * asb.y + b2 * asb.z + b3 * asb.w;
    float rdb = b0 * adb.x + b1 * adb.y + b2 * adb.z + b3 * adb.w;
    #pragma unroll
    for (int off = 1; off < 16; off <<= 1) {
        rsa += __shfl_xor(rsa, off);
        rda += __shfl_xor(rda, off);
        rsb += __shfl_xor(rsb, off);
        rdb += __shfl_xor(rdb, off);
    }
    if ((lane & 15) == 0) {
        const int hh = lane >> 4;
        ssrc8[node * 8 + 0 + hh] = rsa;
        sdst8[node * 8 + 0 + hh] = rda;
        ssrc8[node * 8 + 4 + hh] = rsb;
        sdst8[node * 8 + 4 + hh] = rdb;
    }
}

// ---------- S1: per (node,etype,head) thread computes m and 1/(z+eps) ----------
__global__ __launch_bounds__(256) void seg_mz8_kernel(
        const int* __restrict__ rp_a, const int* __restrict__ cs_a,
        const int* __restrict__ rp_b, const int* __restrict__ cs_b,
        const float* __restrict__ ssrc8, const float* __restrict__ sdst8,
        float* __restrict__ m8, float* __restrict__ zr8) {
    const int t = blockIdx.x * 256 + threadIdx.x;
    if (t >= N_NODES * 8) return;
    const int node = t >> 3;
    const int r8 = t & 7;
    const int et = r8 >> 2;
    const int* rp = et ? rp_b : rp_a;
    const int* cs = et ? cs_b : cs_a;
    const int beg = rp[node], end = rp[node + 1];
    const float sd = sdst8[t];
    float m = -INFINITY;
    for (int e = beg; e < end; e++) {
        float s = ssrc8[cs[e] * 8 + r8] + sd;
        s = (s >= 0.f) ? s : 0.2f * s;
        m = fmaxf(m, s);
    }
    float z = 0.f;
    for (int e = beg; e < end; e++) {
        float s = ssrc8[cs[e] * 8 + r8] + sd;
        s = (s >= 0.f) ? s : 0.2f * s;
        z += expf(s - m);
    }
    m8[t]  = m;
    zr8[t] = 1.f / (z + 1e-16f);
}

// ---------- S2: per (edge,head) alpha in CSR order, one etype ----------
__global__ __launch_bounds__(256) void alpha_kernel(
        const int* __restrict__ cs, const int* __restrict__ cd,
        const float* __restrict__ ssrc8, const float* __restrict__ sdst8,
        const float* __restrict__ m8, const float* __restrict__ zr8,
        float* __restrict__ ebuf, int et) {
    const int t = blockIdx.x * 256 + threadIdx.x;
    if (t >= E_EDGES * NH) return;
    const int pos = t >> 2, hh = t & 3;
    const int r8 = et * 4 + hh;
    const int src = cs[pos], dst = cd[pos];
    float s = ssrc8[src * 8 + r8] + sdst8[dst * 8 + r8];
    s = (s >= 0.f) ? s : 0.2f * s;
    ebuf[t] = expf(s - m8[dst * 8 + r8]) * zr8[dst * 8 + r8];
}

// ---------- S3: aggregation + fused epilogue (bias, leaky, bf16 write) ----------
// Wave per node. Gathers unrolled x4 for memory-level parallelism.
// Writes the layer output DIRECTLY as bf16 (no fp32 acc round-trip).
__global__ __launch_bounds__(256) void aggregate_both_kernel(
        const int* __restrict__ rp_a, const int* __restrict__ cs_a,
        const int* __restrict__ rp_b, const int* __restrict__ cs_b,
        const unsigned short* __restrict__ h_ab,
        const float* __restrict__ ebuf_a, const float* __restrict__ ebuf_b,
        const float* __restrict__ b1, const float* __restrict__ b2,
        unsigned short* __restrict__ out_bf, int do_leaky) {
    const int node = blockIdx.x * 4 + (threadIdx.x >> 6);
    const int lane = threadIdx.x & 63;
    if (node >= N_NODES) return;
    const int hh = lane >> 4;
    const int c4 = lane * 4;

    float4 a = make_float4(0.f, 0.f, 0.f, 0.f);

    #pragma unroll
    for (int et = 0; et < 2; et++) {
        const int* rp = et ? rp_b : rp_a;
        const int* cs = et ? cs_b : cs_a;
        const float* eb = et ? ebuf_b : ebuf_a;
        const size_t hoff = et ? (size_t)HD : 0;
        const int beg = rp[node], end = rp[node + 1];
        int e = beg;
        for (; e + 3 < end; e += 4) {
            const int s0 = cs[e + 0], s1 = cs[e + 1],
                      s2 = cs[e + 2], s3 = cs[e + 3];
            const float al0 = eb[(e + 0) * NH + hh];
            const float al1 = eb[(e + 1) * NH + hh];
            const float al2 = eb[(e + 2) * NH + hh];
            const float al3 = eb[(e + 3) * NH + hh];
            const ushort4 h0 = *(const ushort4*)&h_ab[(size_t)s0 * HD2 + hoff + c4];
            const ushort4 h1 = *(const ushort4*)&h_ab[(size_t)s1 * HD2 + hoff + c4];
            const ushort4 h2 = *(const ushort4*)&h_ab[(size_t)s2 * HD2 + hoff + c4];
            const ushort4 h3 = *(const ushort4*)&h_ab[(size_t)s3 * HD2 + hoff + c4];
            a.x = fmaf(al0, bf2f(h0.x), a.x); a.y = fmaf(al0, bf2f(h0.y), a.y);
            a.z = fmaf(al0, bf2f(h0.z), a.z); a.w = fmaf(al0, bf2f(h0.w), a.w);
            a.x = fmaf(al1, bf2f(h1.x), a.x); a.y = fmaf(al1, bf2f(h1.y), a.y);
            a.z = fmaf(al1, bf2f(h1.z), a.z); a.w = fmaf(al1, bf2f(h1.w), a.w);
            a.x = fmaf(al2, bf2f(h2.x), a.x); a.y = fmaf(al2, bf2f(h2.y), a.y);
            a.z = fmaf(al2, bf2f(h2.z), a.z); a.w = fmaf(al2, bf2f(h2.w), a.w);
            a.x = fmaf(al3, bf2f(h3.x), a.x); a.y = fmaf(al3, bf2f(h3.y), a.y);
            a.z = fmaf(al3, bf2f(h3.z), a.z); a.w = fmaf(al3, bf2f(h3.w), a.w);
        }
        for (; e < end; e++) {
            const int src = cs[e];
            const float al = eb[e * NH + hh];
            const ushort4 hv = *(const ushort4*)&h_ab[(size_t)src * HD2 + hoff + c4];
            a.x = fmaf(al, bf2f(hv.x), a.x);
            a.y = fmaf(al, bf2f(hv.y), a.y);
            a.z = fmaf(al, bf2f(hv.z), a.z);
            a.w = fmaf(al, bf2f(hv.w), a.w);
        }
    }

    const float4 bv1 = *(const float4*)&b1[c4];
    const float4 bv2 = *(const float4*)&b2[c4];
    float4 v;
    v.x = a.x + bv1.x + bv2.x;
    v.y = a.y + bv1.y + bv2.y;
    v.z = a.z + bv1.z + bv2.z;
    v.w = a.w + bv1.w + bv2.w;
    if (do_leaky) {
        v.x = (v.x >= 0.f) ? v.x : 0.01f * v.x;
        v.y = (v.y >= 0.f) ? v.y : 0.01f * v.y;
        v.z = (v.z >= 0.f) ? v.z : 0.01f * v.z;
        v.w = (v.w >= 0.f) ? v.w : 0.01f * v.w;
    }
    ushort4 o;
    o.x = f2bf(v.x); o.y = f2bf(v.y); o.z = f2bf(v.z); o.w = f2bf(v.w);
    *(ushort4*)&out_bf[(size_t)node * HD + c4] = o;
}

// ---------- host-side helpers ----------
static void run_layer(const unsigned short* a_bf,
                      const int* rp_a, const int* cs_a, const int* cd_a,
                      const int* rp_b, const int* cs_b, const int* cd_b,
                      const float* Wa, const float* Wb,
                      const float* as_a, const float* ad_a,
                      const float* as_b, const float* ad_b,
                      const float* b1, const float* b2,
                      unsigned short* Wt2, unsigned short* h_ab,
                      float* ssrc8, float* sdst8, float* m8, float* zr8,
                      float* ebuf_a, float* ebuf_b,
                      unsigned short* out_bf, int do_leaky,
                      hipStream_t stream) {
    wt2_kernel<<<HD2, 256, 0, stream>>>(Wa, Wb, Wt2);
    dim3 ggrid((N_NODES + 255) / 256, HD2 / 64);
    gemm_k256<<<ggrid, 256, 0, stream>>>(a_bf, Wt2, nullptr, h_ab, nullptr,
                                         N_NODES, HD2);
    scores2_kernel<<<(N_NODES + 3) / 4, 256, 0, stream>>>(
        h_ab, as_a, ad_a, as_b, ad_b, ssrc8, sdst8);
    seg_mz8_kernel<<<(N_NODES * 8 + 255) / 256, 256, 0, stream>>>(
        rp_a, cs_a, rp_b, cs_b, ssrc8, sdst8, m8, zr8);
    const int ab = (E_EDGES * NH + 255) / 256;
    alpha_kernel<<<ab, 256, 0, stream>>>(cs_a, cd_a, ssrc8, sdst8, m8, zr8, ebuf_a, 0);
    alpha_kernel<<<ab, 256, 0, stream>>>(cs_b, cd_b, ssrc8, sdst8, m8, zr8, ebuf_b, 1);
    aggregate_both_kernel<<<(N_NODES + 3) / 4, 256, 0, stream>>>(
        rp_a, cs_a, rp_b, cs_b, h_ab, ebuf_a, ebuf_b, b1, b2, out_bf, do_leaky);
}

static void build_csr(const int* ei, int* deg, int* cursor, int* row_ptr,
                      int* col_src, int* col_dst, int* excl, int* bsums,
                      hipStream_t stream) {
    const int nb  = (N_NODES + 255) / 256;
    const int eb  = (E_EDGES + 255) / 256;
    const int sb  = (N_NODES + 1023) / 1024;
    zero_int_kernel<<<nb, 256, 0, stream>>>(deg, N_NODES);
    hist_kernel<<<eb, 256, 0, stream>>>(ei, deg);
    scan_local_kernel<<<sb, 1024, 0, stream>>>(deg, excl, bsums, N_NODES);
    scan_bsums_kernel<<<1, 64, 0, stream>>>(bsums, row_ptr, sb, N_NODES);
    scan_add_kernel<<<nb, 256, 0, stream>>>(excl, bsums, row_ptr, cursor, N_NODES);
    scatter_kernel<<<eb, 256, 0, stream>>>(ei, cursor, col_src, col_dst);
}

extern "C" void kernel_launch(void* const* d_in, const int* in_sizes, int n_in,
                              void* d_out, int out_size, void* d_ws, size_t ws_size,
                              hipStream_t stream) {
    const float* x    = (const float*)d_in[0];
    const int*   ei_a = (const int*)d_in[1];
    const int*   ei_b = (const int*)d_in[2];
    const float* W0a = (const float*)d_in[3];
    const float* as0a = (const float*)d_in[4];
    const float* ad0a = (const float*)d_in[5];
    const float* b0a = (const float*)d_in[6];
    const float* W0b = (const float*)d_in[7];
    const float* as0b = (const float*)d_in[8];
    const float* ad0b = (const float*)d_in[9];
    const float* b0b = (const float*)d_in[10];
    const float* W1a = (const float*)d_in[11];
    const float* as1a = (const float*)d_in[12];
    const float* ad1a = (const float*)d_in[13];
    const float* b1a = (const float*)d_in[14];
    const float* W1b = (const float*)d_in[15];
    const float* as1b = (const float*)d_in[16];
    const float* ad1b = (const float*)d_in[17];
    const float* b1b = (const float*)d_in[18];
    const float* Wout = (const float*)d_in[19];
    const float* bout = (const float*)d_in[20];
    float* out = (float*)d_out;

    // workspace carve
    unsigned short* h_ab  = (unsigned short*)d_ws;          // N*512 ushort
    unsigned short* bf_in = h_ab + (size_t)N_NODES * HD2;   // N*256 ushort
    unsigned short* Wt2   = bf_in + (size_t)N_NODES * HD;   // 512*256 ushort
    float* ssrc8  = (float*)(Wt2 + (size_t)HD2 * KDIM);     // N*8
    float* sdst8  = ssrc8 + (size_t)N_NODES * 8;            // N*8
    float* m8     = sdst8 + (size_t)N_NODES * 8;            // N*8
    float* zr8    = m8 + (size_t)N_NODES * 8;               // N*8
    float* ebuf_a = zr8 + (size_t)N_NODES * 8;              // E*4
    float* ebuf_b = ebuf_a + (size_t)E_EDGES * NH;          // E*4
    int*   ibase  = (int*)(ebuf_b + (size_t)E_EDGES * NH);
    int* deg     = ibase;
    int* cursor  = deg + N_NODES;
    int* rp_a    = cursor + N_NODES;
    int* cs_a    = rp_a + N_NODES + 1;
    int* cd_a    = cs_a + E_EDGES;
    int* rp_b    = cd_a + E_EDGES;
    int* cs_b    = rp_b + N_NODES + 1;
    int* cd_b    = cs_b + E_EDGES;
    int* excl    = cd_b + E_EDGES;
    int* bsums   = excl + N_NODES;

    const size_t NF = (size_t)N_NODES * HD;
    const int nf4_blocks = (int)((NF / 4 + 255) / 256);

    // ---- CSR for both edge types (reused by both layers) ----
    build_csr(ei_a, deg, cursor, rp_a, cs_a, cd_a, excl, bsums, stream);
    build_csr(ei_b, deg, cursor, rp_b, cs_b, cd_b, excl, bsums, stream);

    // ---- layer 0 ----
    convert_bf16_kernel<<<nf4_blocks, 256, 0, stream>>>(x, bf_in, (int)NF);
    run_layer(bf_in, rp_a, cs_a, cd_a, rp_b, cs_b, cd_b, W0a, W0b,
              as0a, ad0a, as0b, ad0b, b0a, b0b, Wt2, h_ab,
              ssrc8, sdst8, m8, zr8, ebuf_a, ebuf_b,
              bf_in, /*leaky=*/1, stream);

    // ---- layer 1 ----
    run_layer(bf_in, rp_a, cs_a, cd_a, rp_b, cs_b, cd_b, W1a, W1b,
              as1a, ad1a, as1b, ad1b, b1a, b1b, Wt2, h_ab,
              ssrc8, sdst8, m8, zr8, ebuf_a, ebuf_b,
              bf_in, /*leaky=*/0, stream);

    // ---- output projection ----
    wt_kernel<<<KDIM, 256, 0, stream>>>(Wout, Wt2, NC);
    dim3 ogrid((N_NODES + 255) / 256, 3);   // 3 x 64 cols covers NC=153
    gemm_k256<<<ogrid, 256, 0, stream>>>(bf_in, Wt2, out, nullptr, bout,
                                         N_NODES, NC);
}